// Round 11
// baseline (170.604 us; speedup 1.0000x reference)
//
#include <hip/hip_runtime.h>

#define NPTS 8192
#define NSLICE 64
#define SLICE_LEN (NPTS / NSLICE)
#define KNN 8
#define SURV_CAP 48
#define TQ 32  // queries per thresh block

typedef short bf16x8 __attribute__((ext_vector_type(8)));
typedef float f32x4 __attribute__((ext_vector_type(4)));

// bf16 round-to-nearest-even split helpers.
__device__ __forceinline__ unsigned short f2bf(float x) {
  unsigned int u = __float_as_uint(x);
  return (unsigned short)((u + 0x7FFF + ((u >> 16) & 1)) >> 16);
}
__device__ __forceinline__ float bf2f(unsigned short s) {
  return __uint_as_float(((unsigned int)s) << 16);
}

// Distance helpers. contract(off) pins the value DAG (r3 failure lesson).
// vals STAGES the float4s that collect later reads (same bits by
// construction); inflated thresholds add a second safety net.
__device__ __forceinline__ float dist_exact(float qx, float qy, float qz,
                                            float q2, float px, float py,
                                            float pz, float p2) {
#pragma clang fp contract(off)
  float dot = __fmaf_rn(qz, pz, __fmaf_rn(qy, py, __fmul_rn(qx, px)));
  float t1 = __fadd_rn(q2, p2);
  return __fadd_rn(t1, __fmul_rn(-2.0f, dot));
}

__device__ __forceinline__ float norm2_exact(float x, float y, float z) {
#pragma clang fp contract(off)
  return __fadd_rn(__fadd_rn(__fmul_rn(x, x), __fmul_rn(y, y)),
                   __fmul_rn(z, z));
}

__device__ __forceinline__ float med3(float a, float b, float c) {
  return __builtin_amdgcn_fmed3f(a, b, c);
}

// Monotone (d, idx) -> f64 key (used only in the tiny final sort).
__device__ __forceinline__ double pack_key(float d, int idx) {
  unsigned int ub = __float_as_uint(d);
  ub ^= (((unsigned int)((int)ub >> 31)) | 0x80000000u);
  unsigned int lo = (ub << 13) | (unsigned int)idx;
  unsigned int hi = 0x3ff00000u | (ub >> 19);
  return __hiloint2double((int)hi, (int)lo);
}

#define KEY_DECL                                                            \
  const double KINF = __longlong_as_double(0x7ff0000000000000LL);           \
  double k0 = KINF, k1 = KINF, k2 = KINF, k3 = KINF, k4 = KINF, k5 = KINF,  \
         k6 = KINF, k7 = KINF;
#define KB1(s)                                                              \
  {                                                                         \
    double mn = fmin(carry, k##s);                                          \
    carry = fmax(carry, k##s);                                              \
    k##s = mn;                                                              \
  }
#define KEY_INSERT(key)                                                     \
  {                                                                         \
    double carry = (key);                                                   \
    KB1(0) KB1(1) KB1(2) KB1(3) KB1(4) KB1(5) KB1(6) KB1(7)                 \
  }

// f32 value-only sorted-8 insert: 7 med3 + 1 min, in-place descending.
#define VINS(dv)                                                            \
  {                                                                         \
    float dd = (dv);                                                        \
    v7 = med3(dd, v6, v7);                                                  \
    v6 = med3(dd, v5, v6);                                                  \
    v5 = med3(dd, v4, v5);                                                  \
    v4 = med3(dd, v3, v4);                                                  \
    v3 = med3(dd, v2, v3);                                                  \
    v2 = med3(dd, v1, v2);                                                  \
    v1 = med3(dd, v0, v1);                                                  \
    v0 = fminf(dd, v0);                                                     \
  }

#define VDECL                                                               \
  const float FINF = __uint_as_float(0x7f800000u);                          \
  float v0 = FINF, v1 = FINF, v2 = FINF, v3 = FINF, v4 = FINF, v5 = FINF,   \
        v6 = FINF, v7 = FINF;

// f32 value-only sorted-2 insert (slice-local): 2 ops.
#define VINS2(dv)                                                           \
  {                                                                         \
    float dd = (dv);                                                        \
    s1 = med3(dd, s0, s1);                                                  \
    s0 = fminf(dd, s0);                                                     \
  }

// ---------------------------------------------------------------------------
// KNN A: per (query, slice of 128) keep the 2 smallest DISTANCE VALUES.
// Top-2 suffices (r8, verified). Blocks with blockIdx.x==0 also publish the
// staged float4 (x,y,z,norm2) to pts4 -- collect later reads EXACTLY these
// bits, so vals/collect candidate bit-identity holds by construction.
// Output part_v[(slice*2+rank)*NPTS+q].
// ---------------------------------------------------------------------------
__global__ __launch_bounds__(256) void knn_vals_kernel(
    const float* __restrict__ pts, float* __restrict__ part_v,
    float4* __restrict__ pts4) {
  __shared__ float4 sp[SLICE_LEN];
  const int t = threadIdx.x;
  const int q = blockIdx.x * 256 + t;
  const int jbase = blockIdx.y * SLICE_LEN;
  for (int p = t; p < SLICE_LEN; p += 256) {
    float x = pts[(jbase + p) * 3 + 0];
    float yy = pts[(jbase + p) * 3 + 1];
    float z = pts[(jbase + p) * 3 + 2];
    float4 v = make_float4(x, yy, z, norm2_exact(x, yy, z));
    sp[p] = v;
    if (blockIdx.x == 0) pts4[jbase + p] = v;
  }
  __syncthreads();
  const float qx = pts[q * 3 + 0], qy = pts[q * 3 + 1], qz = pts[q * 3 + 2];
  const float q2 = norm2_exact(qx, qy, qz);
  const float FINF = __uint_as_float(0x7f800000u);
  float s0 = FINF, s1 = FINF;
  for (int p = 0; p < SLICE_LEN; p += 8) {
    float4 c0 = sp[p + 0];
    float4 c1 = sp[p + 1];
    float4 c2 = sp[p + 2];
    float4 c3 = sp[p + 3];
    float4 c4 = sp[p + 4];
    float4 c5 = sp[p + 5];
    float4 c6 = sp[p + 6];
    float4 c7 = sp[p + 7];
    float d0 = dist_exact(qx, qy, qz, q2, c0.x, c0.y, c0.z, c0.w);
    float d1 = dist_exact(qx, qy, qz, q2, c1.x, c1.y, c1.z, c1.w);
    float d2 = dist_exact(qx, qy, qz, q2, c2.x, c2.y, c2.z, c2.w);
    float d3 = dist_exact(qx, qy, qz, q2, c3.x, c3.y, c3.z, c3.w);
    float d4 = dist_exact(qx, qy, qz, q2, c4.x, c4.y, c4.z, c4.w);
    float d5 = dist_exact(qx, qy, qz, q2, c5.x, c5.y, c5.z, c5.w);
    float d6 = dist_exact(qx, qy, qz, q2, c6.x, c6.y, c6.z, c6.w);
    float d7 = dist_exact(qx, qy, qz, q2, c7.x, c7.y, c7.z, c7.w);
    VINS2(d0);
    VINS2(d1);
    VINS2(d2);
    VINS2(d3);
    VINS2(d4);
    VINS2(d5);
    VINS2(d6);
    VINS2(d7);
  }
  float* o = &part_v[(size_t)(blockIdx.y * 2) * NPTS + q];
  o[0 * NPTS] = s0;
  o[1 * NPTS] = s1;
}

// ---------------------------------------------------------------------------
// KNN B (parallel merge): 8 threads/query over the 128-value pool (64x2).
// tau = pool 8th-smallest >= true v8. Inflated thresholds; collect gathers
// a small superset; final key-sort == jax.lax.top_k order.
// ---------------------------------------------------------------------------
__global__ __launch_bounds__(256) void knn_thresh_kernel(
    const float* __restrict__ part_v, float* __restrict__ thr,
    unsigned long long* __restrict__ mask) {
  __shared__ float v8s[TQ][8][9];   // [lq][chunk][rank]
  __shared__ float smin[TQ][65];    // slice mins
  const int t = threadIdx.x;
  const int lq = t >> 3, c = t & 7;
  const int q = blockIdx.x * TQ + lq;
  {
    VDECL;
#pragma unroll
    for (int s8 = 0; s8 < 8; ++s8) {
      const int s = c * 8 + s8;
      const float* col = &part_v[(size_t)(s * 2) * NPTS + q];
      float a0 = col[0 * (size_t)NPTS];
      float a1 = col[1 * (size_t)NPTS];
      smin[lq][s] = a0;
      VINS(a0);
      VINS(a1);
    }
    v8s[lq][c][0] = v0;
    v8s[lq][c][1] = v1;
    v8s[lq][c][2] = v2;
    v8s[lq][c][3] = v3;
    v8s[lq][c][4] = v4;
    v8s[lq][c][5] = v5;
    v8s[lq][c][6] = v6;
    v8s[lq][c][7] = v7;
  }
  __syncthreads();
  if (c == 0) {
    VDECL;
#pragma unroll
    for (int s = 0; s < 8; ++s) {
      VINS(v8s[lq][s][0]);
      VINS(v8s[lq][s][1]);
      VINS(v8s[lq][s][2]);
      VINS(v8s[lq][s][3]);
      VINS(v8s[lq][s][4]);
      VINS(v8s[lq][s][5]);
      VINS(v8s[lq][s][6]);
      VINS(v8s[lq][s][7]);
    }
    const float tcol = v7 + fabsf(v7) * 4e-5f + 1e-20f;
    const float tmask = v7 + fabsf(v7) * 8e-5f + 2e-20f;
    unsigned long long mk = 0;
#pragma unroll
    for (int s = 0; s < NSLICE; ++s) {
      if (smin[lq][s] <= tmask) mk |= (1ull << s);
    }
    thr[q] = tcol;
    mask[q] = mk;
  }
}

// ---------------------------------------------------------------------------
// KNN C (fused collect+final+weight-prep): one WAVE per query; scan marked
// slices only; survivors to LDS keybuf via atomics; lane 0 key-sorts and
// writes nbr. First 128 blocks ALSO do the weight bf16-splits (consumed by
// gemm1/gemm_ac/gemm2, which launch after this kernel completes):
//   W4  (128x256)  -> W4t[col 256][k 128]  hi/lo
//   Wcat(128x256)  -> W3t[col 256][k 128]  hi/lo (Wcat from W3's halves)
//   W2  (64x128)   -> W2t[col 128][k 64]   hi/lo
// ---------------------------------------------------------------------------
__global__ __launch_bounds__(256) void knn_collect_kernel(
    const float4* __restrict__ pts4, const float* __restrict__ thr,
    const unsigned long long* __restrict__ mask, int* __restrict__ nbr,
    const float* __restrict__ W2, const float* __restrict__ W3,
    const float* __restrict__ W4, unsigned short* __restrict__ W2th,
    unsigned short* __restrict__ W2tl, unsigned short* __restrict__ W3th,
    unsigned short* __restrict__ W3tl, unsigned short* __restrict__ W4ht,
    unsigned short* __restrict__ W4lt) {
  __shared__ double keybuf[4][SURV_CAP];
  __shared__ int scnt[4];
  const int t = threadIdx.x;
  if (blockIdx.x < 128) {
    const int id = blockIdx.x * 256 + t;  // 0..32767
    const int k = id >> 8, c = id & 255;
    {
      float v = W4[k * 256 + c];
      unsigned short hi = f2bf(v);
      W4ht[c * 128 + k] = hi;
      W4lt[c * 128 + k] = f2bf(v - bf2f(hi));
    }
    {
      float v3 = (c < 128) ? W3[k * 128 + c] : W3[(128 + k) * 128 + (c - 128)];
      unsigned short h3 = f2bf(v3);
      W3th[c * 128 + k] = h3;
      W3tl[c * 128 + k] = f2bf(v3 - bf2f(h3));
    }
    if (id < NPTS) {
      const int kk = id >> 7, cc = id & 127;
      float v2 = W2[kk * 128 + cc];
      unsigned short h2 = f2bf(v2);
      W2th[cc * 64 + kk] = h2;
      W2tl[cc * 64 + kk] = f2bf(v2 - bf2f(h2));
    }
  }
  const int wv = t >> 6;
  const int lane = t & 63;
  const int q = blockIdx.x * 4 + wv;
  if (lane == 0) scnt[wv] = 0;
  __syncthreads();
  const float4 qp = pts4[q];
  const float qx = qp.x, qy = qp.y, qz = qp.z, q2 = qp.w;
  const float thrq = thr[q];
  unsigned long long m = mask[q];
  while (m) {
    const int s = (int)__ffsll(m) - 1;
    m &= m - 1;
    const int base = s * SLICE_LEN;
#pragma unroll
    for (int r = 0; r < SLICE_LEN / 64; ++r) {
      const int j = base + r * 64 + lane;
      const float4 cp = pts4[j];
      const float d = dist_exact(qx, qy, qz, q2, cp.x, cp.y, cp.z, cp.w);
      if (d <= thrq) {
        int slot = atomicAdd(&scnt[wv], 1);
        if (slot < SURV_CAP) keybuf[wv][slot] = pack_key(d, j);
      }
    }
  }
  __syncthreads();
  if (lane == 0) {
    int c = scnt[wv];
    if (c > SURV_CAP) c = SURV_CAP;
    KEY_DECL;
    for (int u = 0; u < c; ++u) {
      KEY_INSERT(keybuf[wv][u]);
    }
    int* o = &nbr[q * KNN];
    o[0] = __double2loint(k0) & 0x1fff;
    o[1] = __double2loint(k1) & 0x1fff;
    o[2] = __double2loint(k2) & 0x1fff;
    o[3] = __double2loint(k3) & 0x1fff;
    o[4] = __double2loint(k4) & 0x1fff;
    o[5] = __double2loint(k5) & 0x1fff;
    o[6] = __double2loint(k6) & 0x1fff;
    o[7] = __double2loint(k7) & 0x1fff;
  }
}

// ---------------------------------------------------------------------------
// Fused EdgeConv1 (MFMA, FULL-WIDTH): 64 edges x ALL 128 cols per block --
// es/H1 gather+compute+split done ONCE (was 2x across col-half blocks).
// H1 exact fp32 (K=6) -> bf16 hi/lo LDS; split-bf16 3-pass MFMA; in-register
// max8 + b2 + relu -> y. Fragment layout identical to r9 (verified).
// ---------------------------------------------------------------------------
__global__ __launch_bounds__(256) void gemm1_fused_kernel(
    const float* __restrict__ pts, const int* __restrict__ nbr,
    const float* __restrict__ W1, const float* __restrict__ b1,
    const unsigned short* __restrict__ W2th,
    const unsigned short* __restrict__ W2tl, const float* __restrict__ b2,
    float* __restrict__ y) {
  __shared__ float es[64][6];
  __shared__ float W1s[6][64];
  __shared__ float b1s[64];
  __shared__ unsigned short H1h[64 * 72];
  __shared__ unsigned short H1l[64 * 72];
  __shared__ unsigned short Wth[128 * 72];
  __shared__ unsigned short Wtl[128 * 72];
  const int t = threadIdx.x;
  const int rowBase = blockIdx.x * 64;

  for (int idx = t; idx < 384; idx += 256) W1s[idx >> 6][idx & 63] = W1[idx];
  if (t < 64) b1s[t] = b1[t];
  {
    // Stage W2t: 128 cols x 64 k, 2 threads/col (32 k each), bf16 hi/lo.
    const int colloc = t >> 1, kq = (t & 1) * 32;
    const size_t src = (size_t)colloc * 64 + kq;
    *(uint4*)&Wth[colloc * 72 + kq] = *(const uint4*)&W2th[src];
    *(uint4*)&Wth[colloc * 72 + kq + 8] = *(const uint4*)&W2th[src + 8];
    *(uint4*)&Wth[colloc * 72 + kq + 16] = *(const uint4*)&W2th[src + 16];
    *(uint4*)&Wth[colloc * 72 + kq + 24] = *(const uint4*)&W2th[src + 24];
    *(uint4*)&Wtl[colloc * 72 + kq] = *(const uint4*)&W2tl[src];
    *(uint4*)&Wtl[colloc * 72 + kq + 8] = *(const uint4*)&W2tl[src + 8];
    *(uint4*)&Wtl[colloc * 72 + kq + 16] = *(const uint4*)&W2tl[src + 16];
    *(uint4*)&Wtl[colloc * 72 + kq + 24] = *(const uint4*)&W2tl[src + 24];
  }
  if (t < 64) {
    int e = rowBase + t;
    int i = e >> 3;
    int j = nbr[e];
    float xi0 = pts[i * 3], xi1 = pts[i * 3 + 1], xi2 = pts[i * 3 + 2];
    es[t][0] = xi0;
    es[t][1] = xi1;
    es[t][2] = xi2;
    es[t][3] = pts[j * 3] - xi0;
    es[t][4] = pts[j * 3 + 1] - xi1;
    es[t][5] = pts[j * 3 + 2] - xi2;
  }
  __syncthreads();

  {
    const int e = t & 63, k0 = (t >> 6) * 16;
    const float f0 = es[e][0], f1 = es[e][1], f2 = es[e][2];
    const float f3 = es[e][3], f4 = es[e][4], f5 = es[e][5];
    float h[16];
#pragma unroll
    for (int k = 0; k < 16; ++k) {
      int c = k0 + k;
      float v = b1s[c];
      v = fmaf(f0, W1s[0][c], v);
      v = fmaf(f1, W1s[1][c], v);
      v = fmaf(f2, W1s[2][c], v);
      v = fmaf(f3, W1s[3][c], v);
      v = fmaf(f4, W1s[4][c], v);
      v = fmaf(f5, W1s[5][c], v);
      h[k] = fmaxf(v, 0.0f);
    }
    unsigned int hp[8], lp[8];
#pragma unroll
    for (int u = 0; u < 8; ++u) {
      unsigned short h0 = f2bf(h[2 * u]), h1 = f2bf(h[2 * u + 1]);
      hp[u] = (unsigned int)h0 | ((unsigned int)h1 << 16);
      unsigned short l0 = f2bf(h[2 * u] - bf2f(h0));
      unsigned short l1 = f2bf(h[2 * u + 1] - bf2f(h1));
      lp[u] = (unsigned int)l0 | ((unsigned int)l1 << 16);
    }
    *(uint4*)&H1h[e * 72 + k0] = make_uint4(hp[0], hp[1], hp[2], hp[3]);
    *(uint4*)&H1h[e * 72 + k0 + 8] = make_uint4(hp[4], hp[5], hp[6], hp[7]);
    *(uint4*)&H1l[e * 72 + k0] = make_uint4(lp[0], lp[1], lp[2], lp[3]);
    *(uint4*)&H1l[e * 72 + k0 + 8] = make_uint4(lp[4], lp[5], lp[6], lp[7]);
  }
  __syncthreads();

  const int lane = t & 63, w = t >> 6;
  const int qq = lane >> 4, nidx = lane & 15;
  f32x4 acc[8];
#pragma unroll
  for (int nt = 0; nt < 8; ++nt) acc[nt] = (f32x4){0.f, 0.f, 0.f, 0.f};
  bf16x8 ah0, ah1, al0, al1;
  {
    const int row = w * 16 + nidx;
    ah0 = *(const bf16x8*)&H1h[row * 72 + qq * 8];
    ah1 = *(const bf16x8*)&H1h[row * 72 + 32 + qq * 8];
    al0 = *(const bf16x8*)&H1l[row * 72 + qq * 8];
    al1 = *(const bf16x8*)&H1l[row * 72 + 32 + qq * 8];
  }
#pragma unroll
  for (int nt = 0; nt < 8; ++nt) {
    const int col = nt * 16 + nidx;
    bf16x8 bh0 = *(const bf16x8*)&Wth[col * 72 + qq * 8];
    bf16x8 bh1 = *(const bf16x8*)&Wth[col * 72 + 32 + qq * 8];
    bf16x8 bl0 = *(const bf16x8*)&Wtl[col * 72 + qq * 8];
    bf16x8 bl1 = *(const bf16x8*)&Wtl[col * 72 + 32 + qq * 8];
    acc[nt] = __builtin_amdgcn_mfma_f32_16x16x32_bf16(ah0, bh0, acc[nt], 0, 0, 0);
    acc[nt] = __builtin_amdgcn_mfma_f32_16x16x32_bf16(ah1, bh1, acc[nt], 0, 0, 0);
    acc[nt] = __builtin_amdgcn_mfma_f32_16x16x32_bf16(ah0, bl0, acc[nt], 0, 0, 0);
    acc[nt] = __builtin_amdgcn_mfma_f32_16x16x32_bf16(ah1, bl1, acc[nt], 0, 0, 0);
    acc[nt] = __builtin_amdgcn_mfma_f32_16x16x32_bf16(al0, bh0, acc[nt], 0, 0, 0);
    acc[nt] = __builtin_amdgcn_mfma_f32_16x16x32_bf16(al1, bh1, acc[nt], 0, 0, 0);
  }

  const int pt = blockIdx.x * 8 + 2 * w + (qq >> 1);
#pragma unroll
  for (int nt = 0; nt < 8; ++nt) {
    f32x4 a = acc[nt];
    float m = fmaxf(fmaxf(a[0], a[1]), fmaxf(a[2], a[3]));
    float o = fmaxf(m, __shfl_xor(m, 16, 64));
    if ((qq & 1) == 0) {
      int cg = nt * 16 + nidx;
      y[(size_t)pt * 128 + cg] = fmaxf(o + b2[cg], 0.0f);
    }
  }
}

// ---------------------------------------------------------------------------
// AC = y @ Wcat (+b3 on cols<128) via split-bf16 3-pass MFMA (r10 verified,
// unchanged: 128 rows x 128 cols per block, grid (2,64)).
// ---------------------------------------------------------------------------
__global__ __launch_bounds__(256) void gemm_ac_mfma_kernel(
    const float* __restrict__ y, const unsigned short* __restrict__ W3th,
    const unsigned short* __restrict__ W3tl, const float* __restrict__ bias,
    float* __restrict__ AC) {
  __shared__ unsigned short Ah[128 * 40];
  __shared__ unsigned short Al[128 * 40];
  __shared__ unsigned short Bh[128 * 40];
  __shared__ unsigned short Bl[128 * 40];
  const int t = threadIdx.x;
  const int rowBase = blockIdx.y * 128;
  const int colBase = blockIdx.x * 128;
  const int eloc = t >> 1, hh = t & 1;
  const int kb = hh * 16;
  const int lane = t & 63, w = t >> 6;
  const int q = lane >> 4, nidx = lane & 15;

  f32x4 acc[2][8];
#pragma unroll
  for (int mt = 0; mt < 2; ++mt)
#pragma unroll
    for (int nt = 0; nt < 8; ++nt) acc[mt][nt] = (f32x4){0.f, 0.f, 0.f, 0.f};

  for (int p = 0; p < 4; ++p) {
    const int k0 = p * 32;
    {
      const float* src = &y[(size_t)(rowBase + eloc) * 128 + k0 + kb];
      float h[16];
      *(float4*)&h[0] = *(const float4*)&src[0];
      *(float4*)&h[4] = *(const float4*)&src[4];
      *(float4*)&h[8] = *(const float4*)&src[8];
      *(float4*)&h[12] = *(const float4*)&src[12];
      unsigned int hp[8], lp[8];
#pragma unroll
      for (int u = 0; u < 8; ++u) {
        unsigned short h0 = f2bf(h[2 * u]), h1 = f2bf(h[2 * u + 1]);
        hp[u] = (unsigned int)h0 | ((unsigned int)h1 << 16);
        unsigned short l0 = f2bf(h[2 * u] - bf2f(h0));
        unsigned short l1 = f2bf(h[2 * u + 1] - bf2f(h1));
        lp[u] = (unsigned int)l0 | ((unsigned int)l1 << 16);
      }
      *(uint4*)&Ah[eloc * 40 + kb] = make_uint4(hp[0], hp[1], hp[2], hp[3]);
      *(uint4*)&Ah[eloc * 40 + kb + 8] = make_uint4(hp[4], hp[5], hp[6], hp[7]);
      *(uint4*)&Al[eloc * 40 + kb] = make_uint4(lp[0], lp[1], lp[2], lp[3]);
      *(uint4*)&Al[eloc * 40 + kb + 8] = make_uint4(lp[4], lp[5], lp[6], lp[7]);
    }
    {
      const size_t src = (size_t)(colBase + eloc) * 128 + k0 + kb;
      *(uint4*)&Bh[eloc * 40 + kb] = *(const uint4*)&W3th[src];
      *(uint4*)&Bh[eloc * 40 + kb + 8] = *(const uint4*)&W3th[src + 8];
      *(uint4*)&Bl[eloc * 40 + kb] = *(const uint4*)&W3tl[src];
      *(uint4*)&Bl[eloc * 40 + kb + 8] = *(const uint4*)&W3tl[src + 8];
    }
    __syncthreads();
    bf16x8 ah[2], al[2];
#pragma unroll
    for (int mt = 0; mt < 2; ++mt) {
      int row = w * 32 + mt * 16 + nidx;
      ah[mt] = *(const bf16x8*)&Ah[row * 40 + q * 8];
      al[mt] = *(const bf16x8*)&Al[row * 40 + q * 8];
    }
#pragma unroll
    for (int nt = 0; nt < 8; ++nt) {
      int col = nt * 16 + nidx;
      bf16x8 bh = *(const bf16x8*)&Bh[col * 40 + q * 8];
      bf16x8 bl = *(const bf16x8*)&Bl[col * 40 + q * 8];
#pragma unroll
      for (int mt = 0; mt < 2; ++mt) {
        acc[mt][nt] = __builtin_amdgcn_mfma_f32_16x16x32_bf16(
            ah[mt], bh, acc[mt][nt], 0, 0, 0);
        acc[mt][nt] = __builtin_amdgcn_mfma_f32_16x16x32_bf16(
            ah[mt], bl, acc[mt][nt], 0, 0, 0);
        acc[mt][nt] = __builtin_amdgcn_mfma_f32_16x16x32_bf16(
            al[mt], bh, acc[mt][nt], 0, 0, 0);
      }
    }
    __syncthreads();
  }

#pragma unroll
  for (int mt = 0; mt < 2; ++mt) {
    const int rowb = rowBase + w * 32 + mt * 16 + q * 4;
#pragma unroll
    for (int nt = 0; nt < 8; ++nt) {
      f32x4 a = acc[mt][nt];
      const int cg = colBase + nt * 16 + nidx;
      const float bb = (cg < 128) ? bias[cg] : 0.0f;
#pragma unroll
      for (int reg = 0; reg < 4; ++reg) {
        AC[(size_t)(rowb + reg) * 256 + cg] = a[reg] + bb;
      }
    }
  }
}

// ---------------------------------------------------------------------------
// MFMA EdgeConv2 (FULL-WIDTH): 128 edges x ALL 256 cols per block (grid 512)
// -- the H2 gather (random AC[jp] rows) + bf16 split done ONCE (was 2x).
// LDS 60KB -> 2 blocks/CU. Fragment layout identical to r7/r10 (verified);
// nt loop widened 8 -> 16, acc[2][16].
// ---------------------------------------------------------------------------
__global__ __launch_bounds__(256) void gemm2_mfma_kernel(
    const float* __restrict__ AC, const int* __restrict__ nbr,
    const unsigned short* __restrict__ W4ht,
    const unsigned short* __restrict__ W4lt, const float* __restrict__ b4,
    float* __restrict__ out) {
  __shared__ unsigned short H2h[128 * 40];
  __shared__ unsigned short H2l[128 * 40];
  __shared__ unsigned short Wth[256 * 40];
  __shared__ unsigned short Wtl[256 * 40];
  const int t = threadIdx.x;
  const int rowBase = blockIdx.x * 128;
  const int eloc = t >> 1, hh = t & 1;
  const int kb = hh * 16;
  const int edge = rowBase + eloc;
  const int ip = edge >> 3;
  const int jp = nbr[edge];
  const float* ai_p = AC + (size_t)ip * 256;
  const float* ci_p = ai_p + 128;
  const float* cj_p = AC + (size_t)jp * 256 + 128;
  const int lane = t & 63;
  const int w = t >> 6;
  const int q = lane >> 4;
  const int nidx = lane & 15;

  f32x4 acc[2][16];
#pragma unroll
  for (int mt = 0; mt < 2; ++mt)
#pragma unroll
    for (int nt = 0; nt < 16; ++nt) acc[mt][nt] = (f32x4){0.f, 0.f, 0.f, 0.f};

  for (int p = 0; p < 4; ++p) {
    const int k0 = p * 32;
    {
      float h2[16];
      const float4* a4 = (const float4*)(ai_p + k0 + kb);
      const float4* c4 = (const float4*)(ci_p + k0 + kb);
      const float4* d4 = (const float4*)(cj_p + k0 + kb);
#pragma unroll
      for (int u = 0; u < 4; ++u) {
        float4 a = a4[u], c = c4[u], d = d4[u];
        h2[u * 4 + 0] = fmaxf(a.x + d.x - c.x, 0.f);
        h2[u * 4 + 1] = fmaxf(a.y + d.y - c.y, 0.f);
        h2[u * 4 + 2] = fmaxf(a.z + d.z - c.z, 0.f);
        h2[u * 4 + 3] = fmaxf(a.w + d.w - c.w, 0.f);
      }
      unsigned int hp[8], lp[8];
#pragma unroll
      for (int u = 0; u < 8; ++u) {
        unsigned short h0 = f2bf(h2[2 * u]), h1 = f2bf(h2[2 * u + 1]);
        hp[u] = (unsigned int)h0 | ((unsigned int)h1 << 16);
        unsigned short l0 = f2bf(h2[2 * u] - bf2f(h0));
        unsigned short l1 = f2bf(h2[2 * u + 1] - bf2f(h1));
        lp[u] = (unsigned int)l0 | ((unsigned int)l1 << 16);
      }
      *(uint4*)&H2h[eloc * 40 + kb] = make_uint4(hp[0], hp[1], hp[2], hp[3]);
      *(uint4*)&H2h[eloc * 40 + kb + 8] =
          make_uint4(hp[4], hp[5], hp[6], hp[7]);
      *(uint4*)&H2l[eloc * 40 + kb] = make_uint4(lp[0], lp[1], lp[2], lp[3]);
      *(uint4*)&H2l[eloc * 40 + kb + 8] =
          make_uint4(lp[4], lp[5], lp[6], lp[7]);
    }
    {
      // B stage: 256 cols, 1 thread/col, this phase's 32 ks.
      const size_t src = (size_t)t * 128 + k0;
      *(uint4*)&Wth[t * 40 + 0] = *(const uint4*)&W4ht[src + 0];
      *(uint4*)&Wth[t * 40 + 8] = *(const uint4*)&W4ht[src + 8];
      *(uint4*)&Wth[t * 40 + 16] = *(const uint4*)&W4ht[src + 16];
      *(uint4*)&Wth[t * 40 + 24] = *(const uint4*)&W4ht[src + 24];
      *(uint4*)&Wtl[t * 40 + 0] = *(const uint4*)&W4lt[src + 0];
      *(uint4*)&Wtl[t * 40 + 8] = *(const uint4*)&W4lt[src + 8];
      *(uint4*)&Wtl[t * 40 + 16] = *(const uint4*)&W4lt[src + 16];
      *(uint4*)&Wtl[t * 40 + 24] = *(const uint4*)&W4lt[src + 24];
    }
    __syncthreads();
    bf16x8 ah[2], al[2];
#pragma unroll
    for (int mt = 0; mt < 2; ++mt) {
      int row = w * 32 + mt * 16 + nidx;
      ah[mt] = *(const bf16x8*)&H2h[row * 40 + q * 8];
      al[mt] = *(const bf16x8*)&H2l[row * 40 + q * 8];
    }
#pragma unroll
    for (int nt = 0; nt < 16; ++nt) {
      int col = nt * 16 + nidx;
      bf16x8 bh = *(const bf16x8*)&Wth[col * 40 + q * 8];
      bf16x8 bl = *(const bf16x8*)&Wtl[col * 40 + q * 8];
#pragma unroll
      for (int mt = 0; mt < 2; ++mt) {
        acc[mt][nt] = __builtin_amdgcn_mfma_f32_16x16x32_bf16(
            ah[mt], bh, acc[mt][nt], 0, 0, 0);
        acc[mt][nt] = __builtin_amdgcn_mfma_f32_16x16x32_bf16(
            ah[mt], bl, acc[mt][nt], 0, 0, 0);
        acc[mt][nt] = __builtin_amdgcn_mfma_f32_16x16x32_bf16(
            al[mt], bh, acc[mt][nt], 0, 0, 0);
      }
    }
    __syncthreads();
  }

#pragma unroll
  for (int mt = 0; mt < 2; ++mt) {
    const int ebase = rowBase + w * 32 + mt * 16;
    const int pt0 = ebase >> 3;
#pragma unroll
    for (int nt = 0; nt < 16; ++nt) {
      f32x4 a = acc[mt][nt];
      float m = fmaxf(fmaxf(a[0], a[1]), fmaxf(a[2], a[3]));
      float o = fmaxf(m, __shfl_xor(m, 16, 64));
      int cg = nt * 16 + nidx;
      if (q == 0) {
        out[(size_t)pt0 * 256 + cg] = o + b4[cg];
      } else if (q == 2) {
        out[(size_t)(pt0 + 1) * 256 + cg] = o + b4[cg];
      }
    }
  }
}

extern "C" void kernel_launch(void* const* d_in, const int* in_sizes, int n_in,
                              void* d_out, int out_size, void* d_ws,
                              size_t ws_size, hipStream_t stream) {
  const float* pts = (const float*)d_in[0];
  const float* W1 = (const float*)d_in[1];
  const float* b1 = (const float*)d_in[2];
  const float* W2 = (const float*)d_in[3];
  const float* b2 = (const float*)d_in[4];
  const float* W3 = (const float*)d_in[5];
  const float* b3 = (const float*)d_in[6];
  const float* W4 = (const float*)d_in[7];
  const float* b4 = (const float*)d_in[8];
  float* out = (float*)d_out;

  // Workspace layout (floats), lifetime-overlapped:
  //   part_v [0, 1048576)          : vals->thresh (within AC region)
  //   thr    [4194304, +8192)      : thresh->collect
  //   nbr    [4202496, +65536)     : collect->gemm1/gemm2
  //   y      [4268032, +1048576)   : gemm1->gemm_ac
  //   mask   [5316608, +16384)     : thresh->collect (u64[8192])
  //   W4ht   [5332992, +16384)
  //   W4lt   [5349376, +16384)
  //   pts4   [5365760, +32768)     : vals->collect (f4[8192])
  //   W2th   [5398528, +4096)      : collect->gemm1 (ushort[8192])
  //   W2tl   [5402624, +4096)      : collect->gemm1 (ushort[8192])
  //   W3th   [5406720, +16384)     : collect->gemm_ac (ushort[32768])
  //   W3tl   [5423104, +16384)     : collect->gemm_ac (ushort[32768])
  //   AC = [0, 2097152) (written after part_v is dead)
  float* w = (float*)d_ws;
  float* part_v = w;
  float* thr = w + 4194304;
  int* nbr = (int*)(w + 4202496);
  float* y = w + 4268032;
  unsigned long long* mask = (unsigned long long*)(w + 5316608);
  unsigned short* W4ht = (unsigned short*)(w + 5332992);
  unsigned short* W4lt = (unsigned short*)(w + 5349376);
  float4* pts4 = (float4*)(w + 5365760);
  unsigned short* W2th = (unsigned short*)(w + 5398528);
  unsigned short* W2tl = (unsigned short*)(w + 5402624);
  unsigned short* W3th = (unsigned short*)(w + 5406720);
  unsigned short* W3tl = (unsigned short*)(w + 5423104);
  float* AC = w;

  // 1. KNN: slice top-2 (+pts4 publish) -> pool-merge thresh -> collect
  //    (+weight bf16-splits in first 128 blocks).
  knn_vals_kernel<<<dim3(32, NSLICE), 256, 0, stream>>>(pts, part_v, pts4);
  knn_thresh_kernel<<<NPTS / TQ, 256, 0, stream>>>(part_v, thr, mask);
  knn_collect_kernel<<<2048, 256, 0, stream>>>(pts4, thr, mask, nbr, W2, W3,
                                               W4, W2th, W2tl, W3th, W3tl,
                                               W4ht, W4lt);

  // 2. EdgeConv1 (MFMA H1@W2 + max8 + b2 + relu), full-width blocks.
  gemm1_fused_kernel<<<1024, 256, 0, stream>>>(pts, nbr, W1, b1, W2th, W2tl,
                                               b2, y);

  // 3. EdgeConv2: AC = y@Wcat (+b3) via MFMA, then full-width MFMA
  //    H2+GEMM+max8+b4 -> out.
  gemm_ac_mfma_kernel<<<dim3(2, 64), 256, 0, stream>>>(y, W3th, W3tl, b3, AC);
  gemm2_mfma_kernel<<<512, 256, 0, stream>>>(AC, nbr, W4ht, W4lt, b4, out);
}

// Round 12
// 155.379 us; speedup vs baseline: 1.0980x; 1.0980x over previous
//
#include <hip/hip_runtime.h>

#define NPTS 8192
#define NSLICE 64
#define SLICE_LEN (NPTS / NSLICE)
#define KNN 8
#define SURV_CAP 48
#define TQ 32  // queries per thresh block

typedef short bf16x8 __attribute__((ext_vector_type(8)));
typedef float f32x4 __attribute__((ext_vector_type(4)));

// bf16 round-to-nearest-even split helpers.
__device__ __forceinline__ unsigned short f2bf(float x) {
  unsigned int u = __float_as_uint(x);
  return (unsigned short)((u + 0x7FFF + ((u >> 16) & 1)) >> 16);
}
__device__ __forceinline__ float bf2f(unsigned short s) {
  return __uint_as_float(((unsigned int)s) << 16);
}

// Distance helpers. contract(off) pins the value DAG (r3 failure lesson).
// vals STAGES the float4s that collect later reads (same bits by
// construction); inflated thresholds add a second safety net.
__device__ __forceinline__ float dist_exact(float qx, float qy, float qz,
                                            float q2, float px, float py,
                                            float pz, float p2) {
#pragma clang fp contract(off)
  float dot = __fmaf_rn(qz, pz, __fmaf_rn(qy, py, __fmul_rn(qx, px)));
  float t1 = __fadd_rn(q2, p2);
  return __fadd_rn(t1, __fmul_rn(-2.0f, dot));
}

__device__ __forceinline__ float norm2_exact(float x, float y, float z) {
#pragma clang fp contract(off)
  return __fadd_rn(__fadd_rn(__fmul_rn(x, x), __fmul_rn(y, y)),
                   __fmul_rn(z, z));
}

__device__ __forceinline__ float med3(float a, float b, float c) {
  return __builtin_amdgcn_fmed3f(a, b, c);
}

// Monotone (d, idx) -> f64 key (used only in the tiny final sort).
__device__ __forceinline__ double pack_key(float d, int idx) {
  unsigned int ub = __float_as_uint(d);
  ub ^= (((unsigned int)((int)ub >> 31)) | 0x80000000u);
  unsigned int lo = (ub << 13) | (unsigned int)idx;
  unsigned int hi = 0x3ff00000u | (ub >> 19);
  return __hiloint2double((int)hi, (int)lo);
}

#define KEY_DECL                                                            \
  const double KINF = __longlong_as_double(0x7ff0000000000000LL);           \
  double k0 = KINF, k1 = KINF, k2 = KINF, k3 = KINF, k4 = KINF, k5 = KINF,  \
         k6 = KINF, k7 = KINF;
#define KB1(s)                                                              \
  {                                                                         \
    double mn = fmin(carry, k##s);                                          \
    carry = fmax(carry, k##s);                                              \
    k##s = mn;                                                              \
  }
#define KEY_INSERT(key)                                                     \
  {                                                                         \
    double carry = (key);                                                   \
    KB1(0) KB1(1) KB1(2) KB1(3) KB1(4) KB1(5) KB1(6) KB1(7)                 \
  }

// f32 value-only sorted-8 insert: 7 med3 + 1 min, in-place descending.
#define VINS(dv)                                                            \
  {                                                                         \
    float dd = (dv);                                                        \
    v7 = med3(dd, v6, v7);                                                  \
    v6 = med3(dd, v5, v6);                                                  \
    v5 = med3(dd, v4, v5);                                                  \
    v4 = med3(dd, v3, v4);                                                  \
    v3 = med3(dd, v2, v3);                                                  \
    v2 = med3(dd, v1, v2);                                                  \
    v1 = med3(dd, v0, v1);                                                  \
    v0 = fminf(dd, v0);                                                     \
  }

#define VDECL                                                               \
  const float FINF = __uint_as_float(0x7f800000u);                          \
  float v0 = FINF, v1 = FINF, v2 = FINF, v3 = FINF, v4 = FINF, v5 = FINF,   \
        v6 = FINF, v7 = FINF;

// f32 value-only sorted-2 insert (slice-local): 2 ops.
#define VINS2(dv)                                                           \
  {                                                                         \
    float dd = (dv);                                                        \
    s1 = med3(dd, s0, s1);                                                  \
    s0 = fminf(dd, s0);                                                     \
  }

// ---------------------------------------------------------------------------
// KNN A: per (query, slice of 128) keep the 2 smallest DISTANCE VALUES.
// Top-2 suffices (r8, verified). blockIdx.x==0 blocks also publish the
// staged float4 (x,y,z,norm2) to pts4 -- collect later reads EXACTLY these
// bits, so vals/collect candidate bit-identity holds by construction.
// Output part_v[(slice*2+rank)*NPTS+q].
// ---------------------------------------------------------------------------
__global__ __launch_bounds__(256) void knn_vals_kernel(
    const float* __restrict__ pts, float* __restrict__ part_v,
    float4* __restrict__ pts4) {
  __shared__ float4 sp[SLICE_LEN];
  const int t = threadIdx.x;
  const int q = blockIdx.x * 256 + t;
  const int jbase = blockIdx.y * SLICE_LEN;
  for (int p = t; p < SLICE_LEN; p += 256) {
    float x = pts[(jbase + p) * 3 + 0];
    float yy = pts[(jbase + p) * 3 + 1];
    float z = pts[(jbase + p) * 3 + 2];
    float4 v = make_float4(x, yy, z, norm2_exact(x, yy, z));
    sp[p] = v;
    if (blockIdx.x == 0) pts4[jbase + p] = v;
  }
  __syncthreads();
  const float qx = pts[q * 3 + 0], qy = pts[q * 3 + 1], qz = pts[q * 3 + 2];
  const float q2 = norm2_exact(qx, qy, qz);
  const float FINF = __uint_as_float(0x7f800000u);
  float s0 = FINF, s1 = FINF;
  for (int p = 0; p < SLICE_LEN; p += 8) {
    float4 c0 = sp[p + 0];
    float4 c1 = sp[p + 1];
    float4 c2 = sp[p + 2];
    float4 c3 = sp[p + 3];
    float4 c4 = sp[p + 4];
    float4 c5 = sp[p + 5];
    float4 c6 = sp[p + 6];
    float4 c7 = sp[p + 7];
    float d0 = dist_exact(qx, qy, qz, q2, c0.x, c0.y, c0.z, c0.w);
    float d1 = dist_exact(qx, qy, qz, q2, c1.x, c1.y, c1.z, c1.w);
    float d2 = dist_exact(qx, qy, qz, q2, c2.x, c2.y, c2.z, c2.w);
    float d3 = dist_exact(qx, qy, qz, q2, c3.x, c3.y, c3.z, c3.w);
    float d4 = dist_exact(qx, qy, qz, q2, c4.x, c4.y, c4.z, c4.w);
    float d5 = dist_exact(qx, qy, qz, q2, c5.x, c5.y, c5.z, c5.w);
    float d6 = dist_exact(qx, qy, qz, q2, c6.x, c6.y, c6.z, c6.w);
    float d7 = dist_exact(qx, qy, qz, q2, c7.x, c7.y, c7.z, c7.w);
    VINS2(d0);
    VINS2(d1);
    VINS2(d2);
    VINS2(d3);
    VINS2(d4);
    VINS2(d5);
    VINS2(d6);
    VINS2(d7);
  }
  float* o = &part_v[(size_t)(blockIdx.y * 2) * NPTS + q];
  o[0 * NPTS] = s0;
  o[1 * NPTS] = s1;
}

// ---------------------------------------------------------------------------
// KNN B (parallel merge): 8 threads/query over the 128-value pool (64x2).
// tau = pool 8th-smallest >= true v8. Inflated thresholds; collect gathers
// a small superset; final key-sort == jax.lax.top_k order.
// ---------------------------------------------------------------------------
__global__ __launch_bounds__(256) void knn_thresh_kernel(
    const float* __restrict__ part_v, float* __restrict__ thr,
    unsigned long long* __restrict__ mask) {
  __shared__ float v8s[TQ][8][9];   // [lq][chunk][rank]
  __shared__ float smin[TQ][65];    // slice mins
  const int t = threadIdx.x;
  const int lq = t >> 3, c = t & 7;
  const int q = blockIdx.x * TQ + lq;
  {
    VDECL;
#pragma unroll
    for (int s8 = 0; s8 < 8; ++s8) {
      const int s = c * 8 + s8;
      const float* col = &part_v[(size_t)(s * 2) * NPTS + q];
      float a0 = col[0 * (size_t)NPTS];
      float a1 = col[1 * (size_t)NPTS];
      smin[lq][s] = a0;
      VINS(a0);
      VINS(a1);
    }
    v8s[lq][c][0] = v0;
    v8s[lq][c][1] = v1;
    v8s[lq][c][2] = v2;
    v8s[lq][c][3] = v3;
    v8s[lq][c][4] = v4;
    v8s[lq][c][5] = v5;
    v8s[lq][c][6] = v6;
    v8s[lq][c][7] = v7;
  }
  __syncthreads();
  if (c == 0) {
    VDECL;
#pragma unroll
    for (int s = 0; s < 8; ++s) {
      VINS(v8s[lq][s][0]);
      VINS(v8s[lq][s][1]);
      VINS(v8s[lq][s][2]);
      VINS(v8s[lq][s][3]);
      VINS(v8s[lq][s][4]);
      VINS(v8s[lq][s][5]);
      VINS(v8s[lq][s][6]);
      VINS(v8s[lq][s][7]);
    }
    const float tcol = v7 + fabsf(v7) * 4e-5f + 1e-20f;
    const float tmask = v7 + fabsf(v7) * 8e-5f + 2e-20f;
    unsigned long long mk = 0;
#pragma unroll
    for (int s = 0; s < NSLICE; ++s) {
      if (smin[lq][s] <= tmask) mk |= (1ull << s);
    }
    thr[q] = tcol;
    mask[q] = mk;
  }
}

// ---------------------------------------------------------------------------
// KNN C (fused collect+final+weight-prep): one WAVE per query; scan marked
// slices only; survivors to LDS keybuf via atomics; lane 0 key-sorts and
// writes nbr. First 128 blocks ALSO do the weight bf16-splits (consumed by
// kernels that launch after this one completes).
// ---------------------------------------------------------------------------
__global__ __launch_bounds__(256) void knn_collect_kernel(
    const float4* __restrict__ pts4, const float* __restrict__ thr,
    const unsigned long long* __restrict__ mask, int* __restrict__ nbr,
    const float* __restrict__ W2, const float* __restrict__ W3,
    const float* __restrict__ W4, unsigned short* __restrict__ W2th,
    unsigned short* __restrict__ W2tl, unsigned short* __restrict__ W3th,
    unsigned short* __restrict__ W3tl, unsigned short* __restrict__ W4ht,
    unsigned short* __restrict__ W4lt) {
  __shared__ double keybuf[4][SURV_CAP];
  __shared__ int scnt[4];
  const int t = threadIdx.x;
  if (blockIdx.x < 128) {
    const int id = blockIdx.x * 256 + t;  // 0..32767
    const int k = id >> 8, c = id & 255;
    {
      float v = W4[k * 256 + c];
      unsigned short hi = f2bf(v);
      W4ht[c * 128 + k] = hi;
      W4lt[c * 128 + k] = f2bf(v - bf2f(hi));
    }
    {
      float v3 = (c < 128) ? W3[k * 128 + c] : W3[(128 + k) * 128 + (c - 128)];
      unsigned short h3 = f2bf(v3);
      W3th[c * 128 + k] = h3;
      W3tl[c * 128 + k] = f2bf(v3 - bf2f(h3));
    }
    if (id < NPTS) {
      const int kk = id >> 7, cc = id & 127;
      float v2 = W2[kk * 128 + cc];
      unsigned short h2 = f2bf(v2);
      W2th[cc * 64 + kk] = h2;
      W2tl[cc * 64 + kk] = f2bf(v2 - bf2f(h2));
    }
  }
  const int wv = t >> 6;
  const int lane = t & 63;
  const int q = blockIdx.x * 4 + wv;
  if (lane == 0) scnt[wv] = 0;
  __syncthreads();
  const float4 qp = pts4[q];
  const float qx = qp.x, qy = qp.y, qz = qp.z, q2 = qp.w;
  const float thrq = thr[q];
  unsigned long long m = mask[q];
  while (m) {
    const int s = (int)__ffsll(m) - 1;
    m &= m - 1;
    const int base = s * SLICE_LEN;
#pragma unroll
    for (int r = 0; r < SLICE_LEN / 64; ++r) {
      const int j = base + r * 64 + lane;
      const float4 cp = pts4[j];
      const float d = dist_exact(qx, qy, qz, q2, cp.x, cp.y, cp.z, cp.w);
      if (d <= thrq) {
        int slot = atomicAdd(&scnt[wv], 1);
        if (slot < SURV_CAP) keybuf[wv][slot] = pack_key(d, j);
      }
    }
  }
  __syncthreads();
  if (lane == 0) {
    int c = scnt[wv];
    if (c > SURV_CAP) c = SURV_CAP;
    KEY_DECL;
    for (int u = 0; u < c; ++u) {
      KEY_INSERT(keybuf[wv][u]);
    }
    int* o = &nbr[q * KNN];
    o[0] = __double2loint(k0) & 0x1fff;
    o[1] = __double2loint(k1) & 0x1fff;
    o[2] = __double2loint(k2) & 0x1fff;
    o[3] = __double2loint(k3) & 0x1fff;
    o[4] = __double2loint(k4) & 0x1fff;
    o[5] = __double2loint(k5) & 0x1fff;
    o[6] = __double2loint(k6) & 0x1fff;
    o[7] = __double2loint(k7) & 0x1fff;
  }
}

// ---------------------------------------------------------------------------
// Fused EdgeConv1 (MFMA): H1 = relu(e@W1+b1) exact fp32 (K=6), split to
// bf16 hi/lo in LDS; Y-tile = H1@W2 via split-bf16 3-pass MFMA; in-register
// max8 + b2 + relu -> y (8192x128). As r9/r10 (verified): 64 edges x 64
// cols per block, grid (2,1024), ~37KB LDS -> 4 blocks/CU.
// ---------------------------------------------------------------------------
__global__ __launch_bounds__(256) void gemm1_fused_kernel(
    const float* __restrict__ pts, const int* __restrict__ nbr,
    const float* __restrict__ W1, const float* __restrict__ b1,
    const unsigned short* __restrict__ W2th,
    const unsigned short* __restrict__ W2tl, const float* __restrict__ b2,
    float* __restrict__ y) {
  __shared__ float es[64][6];
  __shared__ float W1s[6][64];
  __shared__ float b1s[64];
  __shared__ unsigned short H1h[64 * 72];
  __shared__ unsigned short H1l[64 * 72];
  __shared__ unsigned short Wth[64 * 72];
  __shared__ unsigned short Wtl[64 * 72];
  const int t = threadIdx.x;
  const int rowBase = blockIdx.y * 64;
  const int colBase = blockIdx.x * 64;

  for (int idx = t; idx < 384; idx += 256) W1s[idx >> 6][idx & 63] = W1[idx];
  if (t < 64) b1s[t] = b1[t];
  {
    const int colloc = t >> 2, kq = (t & 3) * 16;
    const size_t src = (size_t)(colBase + colloc) * 64 + kq;
    *(uint4*)&Wth[colloc * 72 + kq] = *(const uint4*)&W2th[src];
    *(uint4*)&Wth[colloc * 72 + kq + 8] = *(const uint4*)&W2th[src + 8];
    *(uint4*)&Wtl[colloc * 72 + kq] = *(const uint4*)&W2tl[src];
    *(uint4*)&Wtl[colloc * 72 + kq + 8] = *(const uint4*)&W2tl[src + 8];
  }
  if (t < 64) {
    int e = rowBase + t;
    int i = e >> 3;
    int j = nbr[e];
    float xi0 = pts[i * 3], xi1 = pts[i * 3 + 1], xi2 = pts[i * 3 + 2];
    es[t][0] = xi0;
    es[t][1] = xi1;
    es[t][2] = xi2;
    es[t][3] = pts[j * 3] - xi0;
    es[t][4] = pts[j * 3 + 1] - xi1;
    es[t][5] = pts[j * 3 + 2] - xi2;
  }
  __syncthreads();

  {
    const int e = t & 63, k0 = (t >> 6) * 16;
    const float f0 = es[e][0], f1 = es[e][1], f2 = es[e][2];
    const float f3 = es[e][3], f4 = es[e][4], f5 = es[e][5];
    float h[16];
#pragma unroll
    for (int k = 0; k < 16; ++k) {
      int c = k0 + k;
      float v = b1s[c];
      v = fmaf(f0, W1s[0][c], v);
      v = fmaf(f1, W1s[1][c], v);
      v = fmaf(f2, W1s[2][c], v);
      v = fmaf(f3, W1s[3][c], v);
      v = fmaf(f4, W1s[4][c], v);
      v = fmaf(f5, W1s[5][c], v);
      h[k] = fmaxf(v, 0.0f);
    }
    unsigned int hp[8], lp[8];
#pragma unroll
    for (int u = 0; u < 8; ++u) {
      unsigned short h0 = f2bf(h[2 * u]), h1 = f2bf(h[2 * u + 1]);
      hp[u] = (unsigned int)h0 | ((unsigned int)h1 << 16);
      unsigned short l0 = f2bf(h[2 * u] - bf2f(h0));
      unsigned short l1 = f2bf(h[2 * u + 1] - bf2f(h1));
      lp[u] = (unsigned int)l0 | ((unsigned int)l1 << 16);
    }
    *(uint4*)&H1h[e * 72 + k0] = make_uint4(hp[0], hp[1], hp[2], hp[3]);
    *(uint4*)&H1h[e * 72 + k0 + 8] = make_uint4(hp[4], hp[5], hp[6], hp[7]);
    *(uint4*)&H1l[e * 72 + k0] = make_uint4(lp[0], lp[1], lp[2], lp[3]);
    *(uint4*)&H1l[e * 72 + k0 + 8] = make_uint4(lp[4], lp[5], lp[6], lp[7]);
  }
  __syncthreads();

  const int lane = t & 63, w = t >> 6;
  const int qq = lane >> 4, nidx = lane & 15;
  f32x4 acc[4];
#pragma unroll
  for (int nt = 0; nt < 4; ++nt) acc[nt] = (f32x4){0.f, 0.f, 0.f, 0.f};
  bf16x8 ah0, ah1, al0, al1;
  {
    const int row = w * 16 + nidx;
    ah0 = *(const bf16x8*)&H1h[row * 72 + qq * 8];
    ah1 = *(const bf16x8*)&H1h[row * 72 + 32 + qq * 8];
    al0 = *(const bf16x8*)&H1l[row * 72 + qq * 8];
    al1 = *(const bf16x8*)&H1l[row * 72 + 32 + qq * 8];
  }
#pragma unroll
  for (int nt = 0; nt < 4; ++nt) {
    const int col = nt * 16 + nidx;
    bf16x8 bh0 = *(const bf16x8*)&Wth[col * 72 + qq * 8];
    bf16x8 bh1 = *(const bf16x8*)&Wth[col * 72 + 32 + qq * 8];
    bf16x8 bl0 = *(const bf16x8*)&Wtl[col * 72 + qq * 8];
    bf16x8 bl1 = *(const bf16x8*)&Wtl[col * 72 + 32 + qq * 8];
    acc[nt] = __builtin_amdgcn_mfma_f32_16x16x32_bf16(ah0, bh0, acc[nt], 0, 0, 0);
    acc[nt] = __builtin_amdgcn_mfma_f32_16x16x32_bf16(ah1, bh1, acc[nt], 0, 0, 0);
    acc[nt] = __builtin_amdgcn_mfma_f32_16x16x32_bf16(ah0, bl0, acc[nt], 0, 0, 0);
    acc[nt] = __builtin_amdgcn_mfma_f32_16x16x32_bf16(ah1, bl1, acc[nt], 0, 0, 0);
    acc[nt] = __builtin_amdgcn_mfma_f32_16x16x32_bf16(al0, bh0, acc[nt], 0, 0, 0);
    acc[nt] = __builtin_amdgcn_mfma_f32_16x16x32_bf16(al1, bh1, acc[nt], 0, 0, 0);
  }

  const int pt = blockIdx.y * 8 + 2 * w + (qq >> 1);
#pragma unroll
  for (int nt = 0; nt < 4; ++nt) {
    f32x4 a = acc[nt];
    float m = fmaxf(fmaxf(a[0], a[1]), fmaxf(a[2], a[3]));
    float o = fmaxf(m, __shfl_xor(m, 16, 64));
    if ((qq & 1) == 0) {
      int cg = colBase + nt * 16 + nidx;
      y[(size_t)pt * 128 + cg] = fmaxf(o + b2[cg], 0.0f);
    }
  }
}

// ---------------------------------------------------------------------------
// AC = y @ Wcat (+b3 on cols<128) via split-bf16 3-pass MFMA (r10 verified,
// unchanged: 128 rows x 128 cols per block, grid (2,64)).
// ---------------------------------------------------------------------------
__global__ __launch_bounds__(256) void gemm_ac_mfma_kernel(
    const float* __restrict__ y, const unsigned short* __restrict__ W3th,
    const unsigned short* __restrict__ W3tl, const float* __restrict__ bias,
    float* __restrict__ AC) {
  __shared__ unsigned short Ah[128 * 40];
  __shared__ unsigned short Al[128 * 40];
  __shared__ unsigned short Bh[128 * 40];
  __shared__ unsigned short Bl[128 * 40];
  const int t = threadIdx.x;
  const int rowBase = blockIdx.y * 128;
  const int colBase = blockIdx.x * 128;
  const int eloc = t >> 1, hh = t & 1;
  const int kb = hh * 16;
  const int lane = t & 63, w = t >> 6;
  const int q = lane >> 4, nidx = lane & 15;

  f32x4 acc[2][8];
#pragma unroll
  for (int mt = 0; mt < 2; ++mt)
#pragma unroll
    for (int nt = 0; nt < 8; ++nt) acc[mt][nt] = (f32x4){0.f, 0.f, 0.f, 0.f};

  for (int p = 0; p < 4; ++p) {
    const int k0 = p * 32;
    {
      const float* src = &y[(size_t)(rowBase + eloc) * 128 + k0 + kb];
      float h[16];
      *(float4*)&h[0] = *(const float4*)&src[0];
      *(float4*)&h[4] = *(const float4*)&src[4];
      *(float4*)&h[8] = *(const float4*)&src[8];
      *(float4*)&h[12] = *(const float4*)&src[12];
      unsigned int hp[8], lp[8];
#pragma unroll
      for (int u = 0; u < 8; ++u) {
        unsigned short h0 = f2bf(h[2 * u]), h1 = f2bf(h[2 * u + 1]);
        hp[u] = (unsigned int)h0 | ((unsigned int)h1 << 16);
        unsigned short l0 = f2bf(h[2 * u] - bf2f(h0));
        unsigned short l1 = f2bf(h[2 * u + 1] - bf2f(h1));
        lp[u] = (unsigned int)l0 | ((unsigned int)l1 << 16);
      }
      *(uint4*)&Ah[eloc * 40 + kb] = make_uint4(hp[0], hp[1], hp[2], hp[3]);
      *(uint4*)&Ah[eloc * 40 + kb + 8] = make_uint4(hp[4], hp[5], hp[6], hp[7]);
      *(uint4*)&Al[eloc * 40 + kb] = make_uint4(lp[0], lp[1], lp[2], lp[3]);
      *(uint4*)&Al[eloc * 40 + kb + 8] = make_uint4(lp[4], lp[5], lp[6], lp[7]);
    }
    {
      const size_t src = (size_t)(colBase + eloc) * 128 + k0 + kb;
      *(uint4*)&Bh[eloc * 40 + kb] = *(const uint4*)&W3th[src];
      *(uint4*)&Bh[eloc * 40 + kb + 8] = *(const uint4*)&W3th[src + 8];
      *(uint4*)&Bl[eloc * 40 + kb] = *(const uint4*)&W3tl[src];
      *(uint4*)&Bl[eloc * 40 + kb + 8] = *(const uint4*)&W3tl[src + 8];
    }
    __syncthreads();
    bf16x8 ah[2], al[2];
#pragma unroll
    for (int mt = 0; mt < 2; ++mt) {
      int row = w * 32 + mt * 16 + nidx;
      ah[mt] = *(const bf16x8*)&Ah[row * 40 + q * 8];
      al[mt] = *(const bf16x8*)&Al[row * 40 + q * 8];
    }
#pragma unroll
    for (int nt = 0; nt < 8; ++nt) {
      int col = nt * 16 + nidx;
      bf16x8 bh = *(const bf16x8*)&Bh[col * 40 + q * 8];
      bf16x8 bl = *(const bf16x8*)&Bl[col * 40 + q * 8];
#pragma unroll
      for (int mt = 0; mt < 2; ++mt) {
        acc[mt][nt] = __builtin_amdgcn_mfma_f32_16x16x32_bf16(
            ah[mt], bh, acc[mt][nt], 0, 0, 0);
        acc[mt][nt] = __builtin_amdgcn_mfma_f32_16x16x32_bf16(
            ah[mt], bl, acc[mt][nt], 0, 0, 0);
        acc[mt][nt] = __builtin_amdgcn_mfma_f32_16x16x32_bf16(
            al[mt], bh, acc[mt][nt], 0, 0, 0);
      }
    }
    __syncthreads();
  }

#pragma unroll
  for (int mt = 0; mt < 2; ++mt) {
    const int rowb = rowBase + w * 32 + mt * 16 + q * 4;
#pragma unroll
    for (int nt = 0; nt < 8; ++nt) {
      f32x4 a = acc[mt][nt];
      const int cg = colBase + nt * 16 + nidx;
      const float bb = (cg < 128) ? bias[cg] : 0.0f;
#pragma unroll
      for (int reg = 0; reg < 4; ++reg) {
        AC[(size_t)(rowb + reg) * 256 + cg] = a[reg] + bb;
      }
    }
  }
}

// ---------------------------------------------------------------------------
// MFMA EdgeConv2 second layer (split-bf16), as r10 (verified): 128 edges x
// 128 cols per block, grid (2,512), 40KB LDS -> 4 blocks/CU.
// D = Hh*Wh + Hh*Wl + Hl*Wh in fp32 MFMA acc; in-register segmax + b4.
// ---------------------------------------------------------------------------
__global__ __launch_bounds__(256) void gemm2_mfma_kernel(
    const float* __restrict__ AC, const int* __restrict__ nbr,
    const unsigned short* __restrict__ W4ht,
    const unsigned short* __restrict__ W4lt, const float* __restrict__ b4,
    float* __restrict__ out) {
  __shared__ unsigned short H2h[128 * 40];
  __shared__ unsigned short H2l[128 * 40];
  __shared__ unsigned short Wth[128 * 40];
  __shared__ unsigned short Wtl[128 * 40];
  const int t = threadIdx.x;
  const int rowBase = blockIdx.y * 128;
  const int colBase = blockIdx.x * 128;
  const int eloc = t >> 1, hh = t & 1;
  const int kb = hh * 16;
  const int edge = rowBase + eloc;
  const int ip = edge >> 3;
  const int jp = nbr[edge];
  const float* ai_p = AC + (size_t)ip * 256;
  const float* ci_p = ai_p + 128;
  const float* cj_p = AC + (size_t)jp * 256 + 128;
  const int lane = t & 63;
  const int w = t >> 6;
  const int q = lane >> 4;
  const int nidx = lane & 15;

  f32x4 acc[2][8];
#pragma unroll
  for (int mt = 0; mt < 2; ++mt)
#pragma unroll
    for (int nt = 0; nt < 8; ++nt) acc[mt][nt] = (f32x4){0.f, 0.f, 0.f, 0.f};

  for (int p = 0; p < 4; ++p) {
    const int k0 = p * 32;
    {
      float h2[16];
      const float4* a4 = (const float4*)(ai_p + k0 + kb);
      const float4* c4 = (const float4*)(ci_p + k0 + kb);
      const float4* d4 = (const float4*)(cj_p + k0 + kb);
#pragma unroll
      for (int u = 0; u < 4; ++u) {
        float4 a = a4[u], c = c4[u], d = d4[u];
        h2[u * 4 + 0] = fmaxf(a.x + d.x - c.x, 0.f);
        h2[u * 4 + 1] = fmaxf(a.y + d.y - c.y, 0.f);
        h2[u * 4 + 2] = fmaxf(a.z + d.z - c.z, 0.f);
        h2[u * 4 + 3] = fmaxf(a.w + d.w - c.w, 0.f);
      }
      unsigned int hp[8], lp[8];
#pragma unroll
      for (int u = 0; u < 8; ++u) {
        unsigned short h0 = f2bf(h2[2 * u]), h1 = f2bf(h2[2 * u + 1]);
        hp[u] = (unsigned int)h0 | ((unsigned int)h1 << 16);
        unsigned short l0 = f2bf(h2[2 * u] - bf2f(h0));
        unsigned short l1 = f2bf(h2[2 * u + 1] - bf2f(h1));
        lp[u] = (unsigned int)l0 | ((unsigned int)l1 << 16);
      }
      *(uint4*)&H2h[eloc * 40 + kb] = make_uint4(hp[0], hp[1], hp[2], hp[3]);
      *(uint4*)&H2h[eloc * 40 + kb + 8] =
          make_uint4(hp[4], hp[5], hp[6], hp[7]);
      *(uint4*)&H2l[eloc * 40 + kb] = make_uint4(lp[0], lp[1], lp[2], lp[3]);
      *(uint4*)&H2l[eloc * 40 + kb + 8] =
          make_uint4(lp[4], lp[5], lp[6], lp[7]);
    }
    {
      const size_t src = (size_t)(colBase + eloc) * 128 + k0 + kb;
      *(uint4*)&Wth[eloc * 40 + kb] = *(const uint4*)&W4ht[src];
      *(uint4*)&Wth[eloc * 40 + kb + 8] = *(const uint4*)&W4ht[src + 8];
      *(uint4*)&Wtl[eloc * 40 + kb] = *(const uint4*)&W4lt[src];
      *(uint4*)&Wtl[eloc * 40 + kb + 8] = *(const uint4*)&W4lt[src + 8];
    }
    __syncthreads();
    bf16x8 ah[2], al[2];
#pragma unroll
    for (int mt = 0; mt < 2; ++mt) {
      int row = w * 32 + mt * 16 + nidx;
      ah[mt] = *(const bf16x8*)&H2h[row * 40 + q * 8];
      al[mt] = *(const bf16x8*)&H2l[row * 40 + q * 8];
    }
#pragma unroll
    for (int nt = 0; nt < 8; ++nt) {
      int col = nt * 16 + nidx;
      bf16x8 bh = *(const bf16x8*)&Wth[col * 40 + q * 8];
      bf16x8 bl = *(const bf16x8*)&Wtl[col * 40 + q * 8];
#pragma unroll
      for (int mt = 0; mt < 2; ++mt) {
        acc[mt][nt] = __builtin_amdgcn_mfma_f32_16x16x32_bf16(
            ah[mt], bh, acc[mt][nt], 0, 0, 0);
        acc[mt][nt] = __builtin_amdgcn_mfma_f32_16x16x32_bf16(
            ah[mt], bl, acc[mt][nt], 0, 0, 0);
        acc[mt][nt] = __builtin_amdgcn_mfma_f32_16x16x32_bf16(
            al[mt], bh, acc[mt][nt], 0, 0, 0);
      }
    }
    __syncthreads();
  }

#pragma unroll
  for (int mt = 0; mt < 2; ++mt) {
    const int ebase = rowBase + w * 32 + mt * 16;
    const int pt0 = ebase >> 3;
#pragma unroll
    for (int nt = 0; nt < 8; ++nt) {
      f32x4 a = acc[mt][nt];
      float m = fmaxf(fmaxf(a[0], a[1]), fmaxf(a[2], a[3]));
      float o = fmaxf(m, __shfl_xor(m, 16, 64));
      int cg = colBase + nt * 16 + nidx;
      if (q == 0) {
        out[(size_t)pt0 * 256 + cg] = o + b4[cg];
      } else if (q == 2) {
        out[(size_t)(pt0 + 1) * 256 + cg] = o + b4[cg];
      }
    }
  }
}

extern "C" void kernel_launch(void* const* d_in, const int* in_sizes, int n_in,
                              void* d_out, int out_size, void* d_ws,
                              size_t ws_size, hipStream_t stream) {
  const float* pts = (const float*)d_in[0];
  const float* W1 = (const float*)d_in[1];
  const float* b1 = (const float*)d_in[2];
  const float* W2 = (const float*)d_in[3];
  const float* b2 = (const float*)d_in[4];
  const float* W3 = (const float*)d_in[5];
  const float* b3 = (const float*)d_in[6];
  const float* W4 = (const float*)d_in[7];
  const float* b4 = (const float*)d_in[8];
  float* out = (float*)d_out;

  // Workspace layout (floats), lifetime-overlapped:
  //   part_v [0, 1048576)          : vals->thresh (within AC region)
  //   thr    [4194304, +8192)      : thresh->collect
  //   nbr    [4202496, +65536)     : collect->gemm1/gemm2
  //   y      [4268032, +1048576)   : gemm1->gemm_ac
  //   mask   [5316608, +16384)     : thresh->collect (u64[8192])
  //   W4ht   [5332992, +16384)
  //   W4lt   [5349376, +16384)
  //   pts4   [5365760, +32768)     : vals->collect (f4[8192])
  //   W2th   [5398528, +4096)      : collect->gemm1 (ushort[8192])
  //   W2tl   [5402624, +4096)      : collect->gemm1 (ushort[8192])
  //   W3th   [5406720, +16384)     : collect->gemm_ac (ushort[32768])
  //   W3tl   [5423104, +16384)     : collect->gemm_ac (ushort[32768])
  //   AC = [0, 2097152) (written after part_v is dead)
  float* w = (float*)d_ws;
  float* part_v = w;
  float* thr = w + 4194304;
  int* nbr = (int*)(w + 4202496);
  float* y = w + 4268032;
  unsigned long long* mask = (unsigned long long*)(w + 5316608);
  unsigned short* W4ht = (unsigned short*)(w + 5332992);
  unsigned short* W4lt = (unsigned short*)(w + 5349376);
  float4* pts4 = (float4*)(w + 5365760);
  unsigned short* W2th = (unsigned short*)(w + 5398528);
  unsigned short* W2tl = (unsigned short*)(w + 5402624);
  unsigned short* W3th = (unsigned short*)(w + 5406720);
  unsigned short* W3tl = (unsigned short*)(w + 5423104);
  float* AC = w;

  // 1. KNN: slice top-2 (+pts4 publish) -> pool-merge thresh -> collect
  //    (+weight bf16-splits in first 128 blocks).
  knn_vals_kernel<<<dim3(32, NSLICE), 256, 0, stream>>>(pts, part_v, pts4);
  knn_thresh_kernel<<<NPTS / TQ, 256, 0, stream>>>(part_v, thr, mask);
  knn_collect_kernel<<<2048, 256, 0, stream>>>(pts4, thr, mask, nbr, W2, W3,
                                               W4, W2th, W2tl, W3th, W3tl,
                                               W4ht, W4lt);

  // 2. EdgeConv1 (MFMA H1@W2 + max8 + b2 + relu), r10 half-width blocks.
  gemm1_fused_kernel<<<dim3(2, 1024), 256, 0, stream>>>(pts, nbr, W1, b1,
                                                        W2th, W2tl, b2, y);

  // 3. EdgeConv2: AC = y@Wcat (+b3) via MFMA, then r10 MFMA
  //    H2+GEMM+max8+b4 -> out.
  gemm_ac_mfma_kernel<<<dim3(2, 64), 256, 0, stream>>>(y, W3th, W3tl, b3, AC);
  gemm2_mfma_kernel<<<dim3(2, 512), 256, 0, stream>>>(AC, nbr, W4ht, W4lt, b4,
                                                      out);
}

// Round 13
// 153.485 us; speedup vs baseline: 1.1115x; 1.0123x over previous
//
#include <hip/hip_runtime.h>

#define NPTS 8192
#define NSLICE 64
#define SLICE_LEN (NPTS / NSLICE)
#define KNN 8
#define SURV_CAP 48

typedef short bf16x8 __attribute__((ext_vector_type(8)));
typedef float f32x4 __attribute__((ext_vector_type(4)));

// bf16 round-to-nearest-even split helpers.
__device__ __forceinline__ unsigned short f2bf(float x) {
  unsigned int u = __float_as_uint(x);
  return (unsigned short)((u + 0x7FFF + ((u >> 16) & 1)) >> 16);
}
__device__ __forceinline__ float bf2f(unsigned short s) {
  return __uint_as_float(((unsigned int)s) << 16);
}

// Distance helpers. contract(off) pins the value DAG (r3 failure lesson).
// vals STAGES the float4s that collect later reads (same bits by
// construction); inflated thresholds add a second safety net.
__device__ __forceinline__ float dist_exact(float qx, float qy, float qz,
                                            float q2, float px, float py,
                                            float pz, float p2) {
#pragma clang fp contract(off)
  float dot = __fmaf_rn(qz, pz, __fmaf_rn(qy, py, __fmul_rn(qx, px)));
  float t1 = __fadd_rn(q2, p2);
  return __fadd_rn(t1, __fmul_rn(-2.0f, dot));
}

__device__ __forceinline__ float norm2_exact(float x, float y, float z) {
#pragma clang fp contract(off)
  return __fadd_rn(__fadd_rn(__fmul_rn(x, x), __fmul_rn(y, y)),
                   __fmul_rn(z, z));
}

__device__ __forceinline__ float med3(float a, float b, float c) {
  return __builtin_amdgcn_fmed3f(a, b, c);
}

// Monotone (d, idx) -> f64 key (used only in the tiny final sort).
__device__ __forceinline__ double pack_key(float d, int idx) {
  unsigned int ub = __float_as_uint(d);
  ub ^= (((unsigned int)((int)ub >> 31)) | 0x80000000u);
  unsigned int lo = (ub << 13) | (unsigned int)idx;
  unsigned int hi = 0x3ff00000u | (ub >> 19);
  return __hiloint2double((int)hi, (int)lo);
}

#define KEY_DECL                                                            \
  const double KINF = __longlong_as_double(0x7ff0000000000000LL);           \
  double k0 = KINF, k1 = KINF, k2 = KINF, k3 = KINF, k4 = KINF, k5 = KINF,  \
         k6 = KINF, k7 = KINF;
#define KB1(s)                                                              \
  {                                                                         \
    double mn = fmin(carry, k##s);                                          \
    carry = fmax(carry, k##s);                                              \
    k##s = mn;                                                              \
  }
#define KEY_INSERT(key)                                                     \
  {                                                                         \
    double carry = (key);                                                   \
    KB1(0) KB1(1) KB1(2) KB1(3) KB1(4) KB1(5) KB1(6) KB1(7)                 \
  }

// f32 value-only sorted-8 insert: 7 med3 + 1 min, in-place descending.
#define VINS(dv)                                                            \
  {                                                                         \
    float dd = (dv);                                                        \
    v7 = med3(dd, v6, v7);                                                  \
    v6 = med3(dd, v5, v6);                                                  \
    v5 = med3(dd, v4, v5);                                                  \
    v4 = med3(dd, v3, v4);                                                  \
    v3 = med3(dd, v2, v3);                                                  \
    v2 = med3(dd, v1, v2);                                                  \
    v1 = med3(dd, v0, v1);                                                  \
    v0 = fminf(dd, v0);                                                     \
  }

#define VDECL                                                               \
  const float FINF = __uint_as_float(0x7f800000u);                          \
  float v0 = FINF, v1 = FINF, v2 = FINF, v3 = FINF, v4 = FINF, v5 = FINF,   \
        v6 = FINF, v7 = FINF;

// f32 value-only sorted-2 insert (slice-local): 2 ops.
#define VINS2(dv)                                                           \
  {                                                                         \
    float dd = (dv);                                                        \
    s1 = med3(dd, s0, s1);                                                  \
    s0 = fminf(dd, s0);                                                     \
  }

// ---------------------------------------------------------------------------
// KNN A: per (query, slice of 128) keep the 2 smallest DISTANCE VALUES.
// Top-2 suffices (r8, verified). blockIdx.x==0 blocks also publish the
// staged float4 (x,y,z,norm2) to pts4 -- collect later reads EXACTLY these
// bits. Output part_v[(slice*2+rank)*NPTS+q].
// ---------------------------------------------------------------------------
__global__ __launch_bounds__(256) void knn_vals_kernel(
    const float* __restrict__ pts, float* __restrict__ part_v,
    float4* __restrict__ pts4) {
  __shared__ float4 sp[SLICE_LEN];
  const int t = threadIdx.x;
  const int q = blockIdx.x * 256 + t;
  const int jbase = blockIdx.y * SLICE_LEN;
  for (int p = t; p < SLICE_LEN; p += 256) {
    float x = pts[(jbase + p) * 3 + 0];
    float yy = pts[(jbase + p) * 3 + 1];
    float z = pts[(jbase + p) * 3 + 2];
    float4 v = make_float4(x, yy, z, norm2_exact(x, yy, z));
    sp[p] = v;
    if (blockIdx.x == 0) pts4[jbase + p] = v;
  }
  __syncthreads();
  const float qx = pts[q * 3 + 0], qy = pts[q * 3 + 1], qz = pts[q * 3 + 2];
  const float q2 = norm2_exact(qx, qy, qz);
  const float FINF = __uint_as_float(0x7f800000u);
  float s0 = FINF, s1 = FINF;
  for (int p = 0; p < SLICE_LEN; p += 8) {
    float4 c0 = sp[p + 0];
    float4 c1 = sp[p + 1];
    float4 c2 = sp[p + 2];
    float4 c3 = sp[p + 3];
    float4 c4 = sp[p + 4];
    float4 c5 = sp[p + 5];
    float4 c6 = sp[p + 6];
    float4 c7 = sp[p + 7];
    float d0 = dist_exact(qx, qy, qz, q2, c0.x, c0.y, c0.z, c0.w);
    float d1 = dist_exact(qx, qy, qz, q2, c1.x, c1.y, c1.z, c1.w);
    float d2 = dist_exact(qx, qy, qz, q2, c2.x, c2.y, c2.z, c2.w);
    float d3 = dist_exact(qx, qy, qz, q2, c3.x, c3.y, c3.z, c3.w);
    float d4 = dist_exact(qx, qy, qz, q2, c4.x, c4.y, c4.z, c4.w);
    float d5 = dist_exact(qx, qy, qz, q2, c5.x, c5.y, c5.z, c5.w);
    float d6 = dist_exact(qx, qy, qz, q2, c6.x, c6.y, c6.z, c6.w);
    float d7 = dist_exact(qx, qy, qz, q2, c7.x, c7.y, c7.z, c7.w);
    VINS2(d0);
    VINS2(d1);
    VINS2(d2);
    VINS2(d3);
    VINS2(d4);
    VINS2(d5);
    VINS2(d6);
    VINS2(d7);
  }
  float* o = &part_v[(size_t)(blockIdx.y * 2) * NPTS + q];
  o[0 * NPTS] = s0;
  o[1 * NPTS] = s1;
}

// ---------------------------------------------------------------------------
// KNN B+C (fused thresh+collect+final+weight-prep): one block per 4 queries.
// Phase T1 (t<32): per query lq=t>>3, chunk c=t&7 merges 8 slices x 2 ranks
//   (IDENTICAL VINS sequence to the old thresh kernel -> identical tau bits);
//   slice mins stashed in LDS.
// Phase T2 (t<4): final 64-VINS merge -> tau; inflated thresholds
//   tcol=tau*(1+4e-5), tmask=tau*(1+8e-5); mask = slices with min<=tmask.
// Phase C: one WAVE per query scans its ~8 marked slices (~1k candidates);
//   survivors (d<=tcol) -> LDS keybuf via atomics; lane 0 key-sorts the f64
//   (d,idx) keys and writes nbr (== jax.lax.top_k order).
// First 128 blocks ALSO do the weight bf16-splits (consumed by later kernels).
// ---------------------------------------------------------------------------
__global__ __launch_bounds__(256) void knn_collect_kernel(
    const float4* __restrict__ pts4, const float* __restrict__ part_v,
    int* __restrict__ nbr, const float* __restrict__ W2,
    const float* __restrict__ W3, const float* __restrict__ W4,
    unsigned short* __restrict__ W2th, unsigned short* __restrict__ W2tl,
    unsigned short* __restrict__ W3th, unsigned short* __restrict__ W3tl,
    unsigned short* __restrict__ W4ht, unsigned short* __restrict__ W4lt) {
  __shared__ double keybuf[4][SURV_CAP];
  __shared__ int scnt[4];
  __shared__ float v8s[4][8][9];
  __shared__ float smin[4][65];
  __shared__ float thrS[4];
  __shared__ unsigned long long maskS[4];
  const int t = threadIdx.x;
  if (blockIdx.x < 128) {
    const int id = blockIdx.x * 256 + t;  // 0..32767
    const int k = id >> 8, c = id & 255;
    {
      float v = W4[k * 256 + c];
      unsigned short hi = f2bf(v);
      W4ht[c * 128 + k] = hi;
      W4lt[c * 128 + k] = f2bf(v - bf2f(hi));
    }
    {
      float v3 = (c < 128) ? W3[k * 128 + c] : W3[(128 + k) * 128 + (c - 128)];
      unsigned short h3 = f2bf(v3);
      W3th[c * 128 + k] = h3;
      W3tl[c * 128 + k] = f2bf(v3 - bf2f(h3));
    }
    if (id < NPTS) {
      const int kk = id >> 7, cc = id & 127;
      float v2 = W2[kk * 128 + cc];
      unsigned short h2 = f2bf(v2);
      W2th[cc * 64 + kk] = h2;
      W2tl[cc * 64 + kk] = f2bf(v2 - bf2f(h2));
    }
  }
  const int wv = t >> 6;
  const int lane = t & 63;
  const int q = blockIdx.x * 4 + wv;
  if (lane == 0) scnt[wv] = 0;

  // Phase T1: chunk merges (identical structure to the old thresh kernel).
  if (t < 32) {
    const int lq = t >> 3, c = t & 7;
    const int qq = blockIdx.x * 4 + lq;
    VDECL;
#pragma unroll
    for (int s8 = 0; s8 < 8; ++s8) {
      const int s = c * 8 + s8;
      const float* col = &part_v[(size_t)(s * 2) * NPTS + qq];
      float a0 = col[0 * (size_t)NPTS];
      float a1 = col[1 * (size_t)NPTS];
      smin[lq][s] = a0;
      VINS(a0);
      VINS(a1);
    }
    v8s[lq][c][0] = v0;
    v8s[lq][c][1] = v1;
    v8s[lq][c][2] = v2;
    v8s[lq][c][3] = v3;
    v8s[lq][c][4] = v4;
    v8s[lq][c][5] = v5;
    v8s[lq][c][6] = v6;
    v8s[lq][c][7] = v7;
  }
  __syncthreads();

  // Phase T2: final merge + thresholds + slice mask (1 thread per query).
  if (t < 4) {
    const int lq = t;
    VDECL;
#pragma unroll
    for (int s = 0; s < 8; ++s) {
      VINS(v8s[lq][s][0]);
      VINS(v8s[lq][s][1]);
      VINS(v8s[lq][s][2]);
      VINS(v8s[lq][s][3]);
      VINS(v8s[lq][s][4]);
      VINS(v8s[lq][s][5]);
      VINS(v8s[lq][s][6]);
      VINS(v8s[lq][s][7]);
    }
    const float tcol = v7 + fabsf(v7) * 4e-5f + 1e-20f;
    const float tmask = v7 + fabsf(v7) * 8e-5f + 2e-20f;
    unsigned long long mk = 0;
#pragma unroll
    for (int s = 0; s < NSLICE; ++s) {
      if (smin[lq][s] <= tmask) mk |= (1ull << s);
    }
    thrS[lq] = tcol;
    maskS[lq] = mk;
  }
  __syncthreads();

  // Phase C: masked scan.
  const float4 qp = pts4[q];
  const float qx = qp.x, qy = qp.y, qz = qp.z, q2 = qp.w;
  const float thrq = thrS[wv];
  unsigned long long m = maskS[wv];
  while (m) {
    const int s = (int)__ffsll(m) - 1;
    m &= m - 1;
    const int base = s * SLICE_LEN;
#pragma unroll
    for (int r = 0; r < SLICE_LEN / 64; ++r) {
      const int j = base + r * 64 + lane;
      const float4 cp = pts4[j];
      const float d = dist_exact(qx, qy, qz, q2, cp.x, cp.y, cp.z, cp.w);
      if (d <= thrq) {
        int slot = atomicAdd(&scnt[wv], 1);
        if (slot < SURV_CAP) keybuf[wv][slot] = pack_key(d, j);
      }
    }
  }
  __syncthreads();
  if (lane == 0) {
    int c = scnt[wv];
    if (c > SURV_CAP) c = SURV_CAP;
    KEY_DECL;
    for (int u = 0; u < c; ++u) {
      KEY_INSERT(keybuf[wv][u]);
    }
    int* o = &nbr[q * KNN];
    o[0] = __double2loint(k0) & 0x1fff;
    o[1] = __double2loint(k1) & 0x1fff;
    o[2] = __double2loint(k2) & 0x1fff;
    o[3] = __double2loint(k3) & 0x1fff;
    o[4] = __double2loint(k4) & 0x1fff;
    o[5] = __double2loint(k5) & 0x1fff;
    o[6] = __double2loint(k6) & 0x1fff;
    o[7] = __double2loint(k7) & 0x1fff;
  }
}

// ---------------------------------------------------------------------------
// Fused EdgeConv1 (MFMA): H1 = relu(e@W1+b1) exact fp32 (K=6), split to
// bf16 hi/lo in LDS; Y-tile = H1@W2 via split-bf16 3-pass MFMA; in-register
// max8 + b2 + relu -> y (8192x128). As r10/r12 (verified): 64 edges x 64
// cols per block, grid (2,1024).
// ---------------------------------------------------------------------------
__global__ __launch_bounds__(256) void gemm1_fused_kernel(
    const float* __restrict__ pts, const int* __restrict__ nbr,
    const float* __restrict__ W1, const float* __restrict__ b1,
    const unsigned short* __restrict__ W2th,
    const unsigned short* __restrict__ W2tl, const float* __restrict__ b2,
    float* __restrict__ y) {
  __shared__ float es[64][6];
  __shared__ float W1s[6][64];
  __shared__ float b1s[64];
  __shared__ unsigned short H1h[64 * 72];
  __shared__ unsigned short H1l[64 * 72];
  __shared__ unsigned short Wth[64 * 72];
  __shared__ unsigned short Wtl[64 * 72];
  const int t = threadIdx.x;
  const int rowBase = blockIdx.y * 64;
  const int colBase = blockIdx.x * 64;

  for (int idx = t; idx < 384; idx += 256) W1s[idx >> 6][idx & 63] = W1[idx];
  if (t < 64) b1s[t] = b1[t];
  {
    const int colloc = t >> 2, kq = (t & 3) * 16;
    const size_t src = (size_t)(colBase + colloc) * 64 + kq;
    *(uint4*)&Wth[colloc * 72 + kq] = *(const uint4*)&W2th[src];
    *(uint4*)&Wth[colloc * 72 + kq + 8] = *(const uint4*)&W2th[src + 8];
    *(uint4*)&Wtl[colloc * 72 + kq] = *(const uint4*)&W2tl[src];
    *(uint4*)&Wtl[colloc * 72 + kq + 8] = *(const uint4*)&W2tl[src + 8];
  }
  if (t < 64) {
    int e = rowBase + t;
    int i = e >> 3;
    int j = nbr[e];
    float xi0 = pts[i * 3], xi1 = pts[i * 3 + 1], xi2 = pts[i * 3 + 2];
    es[t][0] = xi0;
    es[t][1] = xi1;
    es[t][2] = xi2;
    es[t][3] = pts[j * 3] - xi0;
    es[t][4] = pts[j * 3 + 1] - xi1;
    es[t][5] = pts[j * 3 + 2] - xi2;
  }
  __syncthreads();

  {
    const int e = t & 63, k0 = (t >> 6) * 16;
    const float f0 = es[e][0], f1 = es[e][1], f2 = es[e][2];
    const float f3 = es[e][3], f4 = es[e][4], f5 = es[e][5];
    float h[16];
#pragma unroll
    for (int k = 0; k < 16; ++k) {
      int c = k0 + k;
      float v = b1s[c];
      v = fmaf(f0, W1s[0][c], v);
      v = fmaf(f1, W1s[1][c], v);
      v = fmaf(f2, W1s[2][c], v);
      v = fmaf(f3, W1s[3][c], v);
      v = fmaf(f4, W1s[4][c], v);
      v = fmaf(f5, W1s[5][c], v);
      h[k] = fmaxf(v, 0.0f);
    }
    unsigned int hp[8], lp[8];
#pragma unroll
    for (int u = 0; u < 8; ++u) {
      unsigned short h0 = f2bf(h[2 * u]), h1 = f2bf(h[2 * u + 1]);
      hp[u] = (unsigned int)h0 | ((unsigned int)h1 << 16);
      unsigned short l0 = f2bf(h[2 * u] - bf2f(h0));
      unsigned short l1 = f2bf(h[2 * u + 1] - bf2f(h1));
      lp[u] = (unsigned int)l0 | ((unsigned int)l1 << 16);
    }
    *(uint4*)&H1h[e * 72 + k0] = make_uint4(hp[0], hp[1], hp[2], hp[3]);
    *(uint4*)&H1h[e * 72 + k0 + 8] = make_uint4(hp[4], hp[5], hp[6], hp[7]);
    *(uint4*)&H1l[e * 72 + k0] = make_uint4(lp[0], lp[1], lp[2], lp[3]);
    *(uint4*)&H1l[e * 72 + k0 + 8] = make_uint4(lp[4], lp[5], lp[6], lp[7]);
  }
  __syncthreads();

  const int lane = t & 63, w = t >> 6;
  const int qq = lane >> 4, nidx = lane & 15;
  f32x4 acc[4];
#pragma unroll
  for (int nt = 0; nt < 4; ++nt) acc[nt] = (f32x4){0.f, 0.f, 0.f, 0.f};
  bf16x8 ah0, ah1, al0, al1;
  {
    const int row = w * 16 + nidx;
    ah0 = *(const bf16x8*)&H1h[row * 72 + qq * 8];
    ah1 = *(const bf16x8*)&H1h[row * 72 + 32 + qq * 8];
    al0 = *(const bf16x8*)&H1l[row * 72 + qq * 8];
    al1 = *(const bf16x8*)&H1l[row * 72 + 32 + qq * 8];
  }
#pragma unroll
  for (int nt = 0; nt < 4; ++nt) {
    const int col = nt * 16 + nidx;
    bf16x8 bh0 = *(const bf16x8*)&Wth[col * 72 + qq * 8];
    bf16x8 bh1 = *(const bf16x8*)&Wth[col * 72 + 32 + qq * 8];
    bf16x8 bl0 = *(const bf16x8*)&Wtl[col * 72 + qq * 8];
    bf16x8 bl1 = *(const bf16x8*)&Wtl[col * 72 + 32 + qq * 8];
    acc[nt] = __builtin_amdgcn_mfma_f32_16x16x32_bf16(ah0, bh0, acc[nt], 0, 0, 0);
    acc[nt] = __builtin_amdgcn_mfma_f32_16x16x32_bf16(ah1, bh1, acc[nt], 0, 0, 0);
    acc[nt] = __builtin_amdgcn_mfma_f32_16x16x32_bf16(ah0, bl0, acc[nt], 0, 0, 0);
    acc[nt] = __builtin_amdgcn_mfma_f32_16x16x32_bf16(ah1, bl1, acc[nt], 0, 0, 0);
    acc[nt] = __builtin_amdgcn_mfma_f32_16x16x32_bf16(al0, bh0, acc[nt], 0, 0, 0);
    acc[nt] = __builtin_amdgcn_mfma_f32_16x16x32_bf16(al1, bh1, acc[nt], 0, 0, 0);
  }

  const int pt = blockIdx.y * 8 + 2 * w + (qq >> 1);
#pragma unroll
  for (int nt = 0; nt < 4; ++nt) {
    f32x4 a = acc[nt];
    float m = fmaxf(fmaxf(a[0], a[1]), fmaxf(a[2], a[3]));
    float o = fmaxf(m, __shfl_xor(m, 16, 64));
    if ((qq & 1) == 0) {
      int cg = colBase + nt * 16 + nidx;
      y[(size_t)pt * 128 + cg] = fmaxf(o + b2[cg], 0.0f);
    }
  }
}

// ---------------------------------------------------------------------------
// AC = y @ Wcat (+b3 on cols<128) via split-bf16 3-pass MFMA (r10 verified,
// unchanged: 128 rows x 128 cols per block, grid (2,64)).
// ---------------------------------------------------------------------------
__global__ __launch_bounds__(256) void gemm_ac_mfma_kernel(
    const float* __restrict__ y, const unsigned short* __restrict__ W3th,
    const unsigned short* __restrict__ W3tl, const float* __restrict__ bias,
    float* __restrict__ AC) {
  __shared__ unsigned short Ah[128 * 40];
  __shared__ unsigned short Al[128 * 40];
  __shared__ unsigned short Bh[128 * 40];
  __shared__ unsigned short Bl[128 * 40];
  const int t = threadIdx.x;
  const int rowBase = blockIdx.y * 128;
  const int colBase = blockIdx.x * 128;
  const int eloc = t >> 1, hh = t & 1;
  const int kb = hh * 16;
  const int lane = t & 63, w = t >> 6;
  const int q = lane >> 4, nidx = lane & 15;

  f32x4 acc[2][8];
#pragma unroll
  for (int mt = 0; mt < 2; ++mt)
#pragma unroll
    for (int nt = 0; nt < 8; ++nt) acc[mt][nt] = (f32x4){0.f, 0.f, 0.f, 0.f};

  for (int p = 0; p < 4; ++p) {
    const int k0 = p * 32;
    {
      const float* src = &y[(size_t)(rowBase + eloc) * 128 + k0 + kb];
      float h[16];
      *(float4*)&h[0] = *(const float4*)&src[0];
      *(float4*)&h[4] = *(const float4*)&src[4];
      *(float4*)&h[8] = *(const float4*)&src[8];
      *(float4*)&h[12] = *(const float4*)&src[12];
      unsigned int hp[8], lp[8];
#pragma unroll
      for (int u = 0; u < 8; ++u) {
        unsigned short h0 = f2bf(h[2 * u]), h1 = f2bf(h[2 * u + 1]);
        hp[u] = (unsigned int)h0 | ((unsigned int)h1 << 16);
        unsigned short l0 = f2bf(h[2 * u] - bf2f(h0));
        unsigned short l1 = f2bf(h[2 * u + 1] - bf2f(h1));
        lp[u] = (unsigned int)l0 | ((unsigned int)l1 << 16);
      }
      *(uint4*)&Ah[eloc * 40 + kb] = make_uint4(hp[0], hp[1], hp[2], hp[3]);
      *(uint4*)&Ah[eloc * 40 + kb + 8] = make_uint4(hp[4], hp[5], hp[6], hp[7]);
      *(uint4*)&Al[eloc * 40 + kb] = make_uint4(lp[0], lp[1], lp[2], lp[3]);
      *(uint4*)&Al[eloc * 40 + kb + 8] = make_uint4(lp[4], lp[5], lp[6], lp[7]);
    }
    {
      const size_t src = (size_t)(colBase + eloc) * 128 + k0 + kb;
      *(uint4*)&Bh[eloc * 40 + kb] = *(const uint4*)&W3th[src];
      *(uint4*)&Bh[eloc * 40 + kb + 8] = *(const uint4*)&W3th[src + 8];
      *(uint4*)&Bl[eloc * 40 + kb] = *(const uint4*)&W3tl[src];
      *(uint4*)&Bl[eloc * 40 + kb + 8] = *(const uint4*)&W3tl[src + 8];
    }
    __syncthreads();
    bf16x8 ah[2], al[2];
#pragma unroll
    for (int mt = 0; mt < 2; ++mt) {
      int row = w * 32 + mt * 16 + nidx;
      ah[mt] = *(const bf16x8*)&Ah[row * 40 + q * 8];
      al[mt] = *(const bf16x8*)&Al[row * 40 + q * 8];
    }
#pragma unroll
    for (int nt = 0; nt < 8; ++nt) {
      int col = nt * 16 + nidx;
      bf16x8 bh = *(const bf16x8*)&Bh[col * 40 + q * 8];
      bf16x8 bl = *(const bf16x8*)&Bl[col * 40 + q * 8];
#pragma unroll
      for (int mt = 0; mt < 2; ++mt) {
        acc[mt][nt] = __builtin_amdgcn_mfma_f32_16x16x32_bf16(
            ah[mt], bh, acc[mt][nt], 0, 0, 0);
        acc[mt][nt] = __builtin_amdgcn_mfma_f32_16x16x32_bf16(
            ah[mt], bl, acc[mt][nt], 0, 0, 0);
        acc[mt][nt] = __builtin_amdgcn_mfma_f32_16x16x32_bf16(
            al[mt], bh, acc[mt][nt], 0, 0, 0);
      }
    }
    __syncthreads();
  }

#pragma unroll
  for (int mt = 0; mt < 2; ++mt) {
    const int rowb = rowBase + w * 32 + mt * 16 + q * 4;
#pragma unroll
    for (int nt = 0; nt < 8; ++nt) {
      f32x4 a = acc[mt][nt];
      const int cg = colBase + nt * 16 + nidx;
      const float bb = (cg < 128) ? bias[cg] : 0.0f;
#pragma unroll
      for (int reg = 0; reg < 4; ++reg) {
        AC[(size_t)(rowb + reg) * 256 + cg] = a[reg] + bb;
      }
    }
  }
}

// ---------------------------------------------------------------------------
// MFMA EdgeConv2 second layer (split-bf16), as r10/r12 (verified): 128
// edges x 128 cols per block, grid (2,512).
// ---------------------------------------------------------------------------
__global__ __launch_bounds__(256) void gemm2_mfma_kernel(
    const float* __restrict__ AC, const int* __restrict__ nbr,
    const unsigned short* __restrict__ W4ht,
    const unsigned short* __restrict__ W4lt, const float* __restrict__ b4,
    float* __restrict__ out) {
  __shared__ unsigned short H2h[128 * 40];
  __shared__ unsigned short H2l[128 * 40];
  __shared__ unsigned short Wth[128 * 40];
  __shared__ unsigned short Wtl[128 * 40];
  const int t = threadIdx.x;
  const int rowBase = blockIdx.y * 128;
  const int colBase = blockIdx.x * 128;
  const int eloc = t >> 1, hh = t & 1;
  const int kb = hh * 16;
  const int edge = rowBase + eloc;
  const int ip = edge >> 3;
  const int jp = nbr[edge];
  const float* ai_p = AC + (size_t)ip * 256;
  const float* ci_p = ai_p + 128;
  const float* cj_p = AC + (size_t)jp * 256 + 128;
  const int lane = t & 63;
  const int w = t >> 6;
  const int q = lane >> 4;
  const int nidx = lane & 15;

  f32x4 acc[2][8];
#pragma unroll
  for (int mt = 0; mt < 2; ++mt)
#pragma unroll
    for (int nt = 0; nt < 8; ++nt) acc[mt][nt] = (f32x4){0.f, 0.f, 0.f, 0.f};

  for (int p = 0; p < 4; ++p) {
    const int k0 = p * 32;
    {
      float h2[16];
      const float4* a4 = (const float4*)(ai_p + k0 + kb);
      const float4* c4 = (const float4*)(ci_p + k0 + kb);
      const float4* d4 = (const float4*)(cj_p + k0 + kb);
#pragma unroll
      for (int u = 0; u < 4; ++u) {
        float4 a = a4[u], c = c4[u], d = d4[u];
        h2[u * 4 + 0] = fmaxf(a.x + d.x - c.x, 0.f);
        h2[u * 4 + 1] = fmaxf(a.y + d.y - c.y, 0.f);
        h2[u * 4 + 2] = fmaxf(a.z + d.z - c.z, 0.f);
        h2[u * 4 + 3] = fmaxf(a.w + d.w - c.w, 0.f);
      }
      unsigned int hp[8], lp[8];
#pragma unroll
      for (int u = 0; u < 8; ++u) {
        unsigned short h0 = f2bf(h2[2 * u]), h1 = f2bf(h2[2 * u + 1]);
        hp[u] = (unsigned int)h0 | ((unsigned int)h1 << 16);
        unsigned short l0 = f2bf(h2[2 * u] - bf2f(h0));
        unsigned short l1 = f2bf(h2[2 * u + 1] - bf2f(h1));
        lp[u] = (unsigned int)l0 | ((unsigned int)l1 << 16);
      }
      *(uint4*)&H2h[eloc * 40 + kb] = make_uint4(hp[0], hp[1], hp[2], hp[3]);
      *(uint4*)&H2h[eloc * 40 + kb + 8] =
          make_uint4(hp[4], hp[5], hp[6], hp[7]);
      *(uint4*)&H2l[eloc * 40 + kb] = make_uint4(lp[0], lp[1], lp[2], lp[3]);
      *(uint4*)&H2l[eloc * 40 + kb + 8] =
          make_uint4(lp[4], lp[5], lp[6], lp[7]);
    }
    {
      const size_t src = (size_t)(colBase + eloc) * 128 + k0 + kb;
      *(uint4*)&Wth[eloc * 40 + kb] = *(const uint4*)&W4ht[src];
      *(uint4*)&Wth[eloc * 40 + kb + 8] = *(const uint4*)&W4ht[src + 8];
      *(uint4*)&Wtl[eloc * 40 + kb] = *(const uint4*)&W4lt[src];
      *(uint4*)&Wtl[eloc * 40 + kb + 8] = *(const uint4*)&W4lt[src + 8];
    }
    __syncthreads();
    bf16x8 ah[2], al[2];
#pragma unroll
    for (int mt = 0; mt < 2; ++mt) {
      int row = w * 32 + mt * 16 + nidx;
      ah[mt] = *(const bf16x8*)&H2h[row * 40 + q * 8];
      al[mt] = *(const bf16x8*)&H2l[row * 40 + q * 8];
    }
#pragma unroll
    for (int nt = 0; nt < 8; ++nt) {
      int col = nt * 16 + nidx;
      bf16x8 bh = *(const bf16x8*)&Wth[col * 40 + q * 8];
      bf16x8 bl = *(const bf16x8*)&Wtl[col * 40 + q * 8];
#pragma unroll
      for (int mt = 0; mt < 2; ++mt) {
        acc[mt][nt] = __builtin_amdgcn_mfma_f32_16x16x32_bf16(
            ah[mt], bh, acc[mt][nt], 0, 0, 0);
        acc[mt][nt] = __builtin_amdgcn_mfma_f32_16x16x32_bf16(
            ah[mt], bl, acc[mt][nt], 0, 0, 0);
        acc[mt][nt] = __builtin_amdgcn_mfma_f32_16x16x32_bf16(
            al[mt], bh, acc[mt][nt], 0, 0, 0);
      }
    }
    __syncthreads();
  }

#pragma unroll
  for (int mt = 0; mt < 2; ++mt) {
    const int ebase = rowBase + w * 32 + mt * 16;
    const int pt0 = ebase >> 3;
#pragma unroll
    for (int nt = 0; nt < 8; ++nt) {
      f32x4 a = acc[mt][nt];
      float m = fmaxf(fmaxf(a[0], a[1]), fmaxf(a[2], a[3]));
      float o = fmaxf(m, __shfl_xor(m, 16, 64));
      int cg = colBase + nt * 16 + nidx;
      if (q == 0) {
        out[(size_t)pt0 * 256 + cg] = o + b4[cg];
      } else if (q == 2) {
        out[(size_t)(pt0 + 1) * 256 + cg] = o + b4[cg];
      }
    }
  }
}

extern "C" void kernel_launch(void* const* d_in, const int* in_sizes, int n_in,
                              void* d_out, int out_size, void* d_ws,
                              size_t ws_size, hipStream_t stream) {
  const float* pts = (const float*)d_in[0];
  const float* W1 = (const float*)d_in[1];
  const float* b1 = (const float*)d_in[2];
  const float* W2 = (const float*)d_in[3];
  const float* b2 = (const float*)d_in[4];
  const float* W3 = (const float*)d_in[5];
  const float* b3 = (const float*)d_in[6];
  const float* W4 = (const float*)d_in[7];
  const float* b4 = (const float*)d_in[8];
  float* out = (float*)d_out;

  // Workspace layout (floats), lifetime-overlapped:
  //   part_v [0, 1048576)          : vals->collect (within AC region)
  //   nbr    [4202496, +65536)     : collect->gemm1/gemm2
  //   y      [4268032, +1048576)   : gemm1->gemm_ac
  //   W4ht   [5332992, +16384)
  //   W4lt   [5349376, +16384)
  //   pts4   [5365760, +32768)     : vals->collect (f4[8192])
  //   W2th   [5398528, +4096)      : collect->gemm1 (ushort[8192])
  //   W2tl   [5402624, +4096)      : collect->gemm1 (ushort[8192])
  //   W3th   [5406720, +16384)     : collect->gemm_ac (ushort[32768])
  //   W3tl   [5423104, +16384)     : collect->gemm_ac (ushort[32768])
  //   AC = [0, 2097152) (written after part_v is dead)
  float* w = (float*)d_ws;
  float* part_v = w;
  int* nbr = (int*)(w + 4202496);
  float* y = w + 4268032;
  unsigned short* W4ht = (unsigned short*)(w + 5332992);
  unsigned short* W4lt = (unsigned short*)(w + 5349376);
  float4* pts4 = (float4*)(w + 5365760);
  unsigned short* W2th = (unsigned short*)(w + 5398528);
  unsigned short* W2tl = (unsigned short*)(w + 5402624);
  unsigned short* W3th = (unsigned short*)(w + 5406720);
  unsigned short* W3tl = (unsigned short*)(w + 5423104);
  float* AC = w;

  // 1. KNN: slice top-2 (+pts4 publish) -> fused thresh+collect
  //    (+weight bf16-splits in first 128 blocks).
  knn_vals_kernel<<<dim3(32, NSLICE), 256, 0, stream>>>(pts, part_v, pts4);
  knn_collect_kernel<<<2048, 256, 0, stream>>>(pts4, part_v, nbr, W2, W3, W4,
                                               W2th, W2tl, W3th, W3tl, W4ht,
                                               W4lt);

  // 2. EdgeConv1 (MFMA H1@W2 + max8 + b2 + relu), r10 half-width blocks.
  gemm1_fused_kernel<<<dim3(2, 1024), 256, 0, stream>>>(pts, nbr, W1, b1,
                                                        W2th, W2tl, b2, y);

  // 3. EdgeConv2: AC = y@Wcat (+b3) via MFMA, then r10 MFMA
  //    H2+GEMM+max8+b4 -> out.
  gemm_ac_mfma_kernel<<<dim3(2, 64), 256, 0, stream>>>(y, W3th, W3tl, b3, AC);
  gemm2_mfma_kernel<<<dim3(2, 512), 256, 0, stream>>>(AC, nbr, W4ht, W4lt, b4,
                                                      out);
}

// Round 14
// 152.997 us; speedup vs baseline: 1.1151x; 1.0032x over previous
//
#include <hip/hip_runtime.h>

#define NPTS 8192
#define NSLICE 64
#define SLICE_LEN (NPTS / NSLICE)
#define KNN 8
#define SURV_CAP 48

typedef short bf16x8 __attribute__((ext_vector_type(8)));
typedef float f32x4 __attribute__((ext_vector_type(4)));

// bf16 round-to-nearest-even split helpers.
__device__ __forceinline__ unsigned short f2bf(float x) {
  unsigned int u = __float_as_uint(x);
  return (unsigned short)((u + 0x7FFF + ((u >> 16) & 1)) >> 16);
}
__device__ __forceinline__ float bf2f(unsigned short s) {
  return __uint_as_float(((unsigned int)s) << 16);
}

// Packed distance: pts4 holds (-2x,-2y,-2z,p2), so
//   d = q2 + fma(qx,m2x, fma(qy,m2y, fma(qz,m2z, p2)))  -- 4 ops.
// contract(off) pins the value DAG; vals and collect use THIS SAME helper
// on THE SAME pts4 bits -> self-consistent selection; inflated thresholds
// cover any residual ulp noise (r3/r4 lessons).
__device__ __forceinline__ float dist_pk(float qx, float qy, float qz,
                                         float q2, float m2x, float m2y,
                                         float m2z, float p2) {
#pragma clang fp contract(off)
  float s = __fmaf_rn(qz, m2z, __fmaf_rn(qy, m2y, __fmaf_rn(qx, m2x, p2)));
  return __fadd_rn(q2, s);
}

__device__ __forceinline__ float norm2_exact(float x, float y, float z) {
#pragma clang fp contract(off)
  return __fadd_rn(__fadd_rn(__fmul_rn(x, x), __fmul_rn(y, y)),
                   __fmul_rn(z, z));
}

__device__ __forceinline__ float med3(float a, float b, float c) {
  return __builtin_amdgcn_fmed3f(a, b, c);
}

// Monotone (d, idx) -> f64 key (used only in the tiny final sort).
__device__ __forceinline__ double pack_key(float d, int idx) {
  unsigned int ub = __float_as_uint(d);
  ub ^= (((unsigned int)((int)ub >> 31)) | 0x80000000u);
  unsigned int lo = (ub << 13) | (unsigned int)idx;
  unsigned int hi = 0x3ff00000u | (ub >> 19);
  return __hiloint2double((int)hi, (int)lo);
}

#define KEY_DECL                                                            \
  const double KINF = __longlong_as_double(0x7ff0000000000000LL);           \
  double k0 = KINF, k1 = KINF, k2 = KINF, k3 = KINF, k4 = KINF, k5 = KINF,  \
         k6 = KINF, k7 = KINF;
#define KB1(s)                                                              \
  {                                                                         \
    double mn = fmin(carry, k##s);                                          \
    carry = fmax(carry, k##s);                                              \
    k##s = mn;                                                              \
  }
#define KEY_INSERT(key)                                                     \
  {                                                                         \
    double carry = (key);                                                   \
    KB1(0) KB1(1) KB1(2) KB1(3) KB1(4) KB1(5) KB1(6) KB1(7)                 \
  }

// f32 value-only sorted-8 insert: 7 med3 + 1 min, in-place descending.
#define VINS(dv)                                                            \
  {                                                                         \
    float dd = (dv);                                                        \
    v7 = med3(dd, v6, v7);                                                  \
    v6 = med3(dd, v5, v6);                                                  \
    v5 = med3(dd, v4, v5);                                                  \
    v4 = med3(dd, v3, v4);                                                  \
    v3 = med3(dd, v2, v3);                                                  \
    v2 = med3(dd, v1, v2);                                                  \
    v1 = med3(dd, v0, v1);                                                  \
    v0 = fminf(dd, v0);                                                     \
  }

#define VDECL                                                               \
  const float FINF = __uint_as_float(0x7f800000u);                          \
  float v0 = FINF, v1 = FINF, v2 = FINF, v3 = FINF, v4 = FINF, v5 = FINF,   \
        v6 = FINF, v7 = FINF;

// f32 value-only sorted-2 insert (slice-local): 2 ops.
#define VINS2(dv)                                                           \
  {                                                                         \
    float dd = (dv);                                                        \
    s1 = med3(dd, s0, s1);                                                  \
    s0 = fminf(dd, s0);                                                     \
  }

// ---------------------------------------------------------------------------
// KNN A: per (query, slice of 128) keep the 2 smallest DISTANCE VALUES.
// pts4 packing: (-2x,-2y,-2z,norm2); blockIdx.x==0 blocks publish it.
// Queries read raw pts. Output part_v[(slice*2+rank)*NPTS+q].
// ---------------------------------------------------------------------------
__global__ __launch_bounds__(256) void knn_vals_kernel(
    const float* __restrict__ pts, float* __restrict__ part_v,
    float4* __restrict__ pts4) {
  __shared__ float4 sp[SLICE_LEN];
  const int t = threadIdx.x;
  const int q = blockIdx.x * 256 + t;
  const int jbase = blockIdx.y * SLICE_LEN;
  for (int p = t; p < SLICE_LEN; p += 256) {
    float x = pts[(jbase + p) * 3 + 0];
    float yy = pts[(jbase + p) * 3 + 1];
    float z = pts[(jbase + p) * 3 + 2];
    float4 v = make_float4(__fmul_rn(-2.0f, x), __fmul_rn(-2.0f, yy),
                           __fmul_rn(-2.0f, z), norm2_exact(x, yy, z));
    sp[p] = v;
    if (blockIdx.x == 0) pts4[jbase + p] = v;
  }
  __syncthreads();
  const float qx = pts[q * 3 + 0], qy = pts[q * 3 + 1], qz = pts[q * 3 + 2];
  const float q2 = norm2_exact(qx, qy, qz);
  const float FINF = __uint_as_float(0x7f800000u);
  float s0 = FINF, s1 = FINF;
  for (int p = 0; p < SLICE_LEN; p += 8) {
    float4 c0 = sp[p + 0];
    float4 c1 = sp[p + 1];
    float4 c2 = sp[p + 2];
    float4 c3 = sp[p + 3];
    float4 c4 = sp[p + 4];
    float4 c5 = sp[p + 5];
    float4 c6 = sp[p + 6];
    float4 c7 = sp[p + 7];
    float d0 = dist_pk(qx, qy, qz, q2, c0.x, c0.y, c0.z, c0.w);
    float d1 = dist_pk(qx, qy, qz, q2, c1.x, c1.y, c1.z, c1.w);
    float d2 = dist_pk(qx, qy, qz, q2, c2.x, c2.y, c2.z, c2.w);
    float d3 = dist_pk(qx, qy, qz, q2, c3.x, c3.y, c3.z, c3.w);
    float d4 = dist_pk(qx, qy, qz, q2, c4.x, c4.y, c4.z, c4.w);
    float d5 = dist_pk(qx, qy, qz, q2, c5.x, c5.y, c5.z, c5.w);
    float d6 = dist_pk(qx, qy, qz, q2, c6.x, c6.y, c6.z, c6.w);
    float d7 = dist_pk(qx, qy, qz, q2, c7.x, c7.y, c7.z, c7.w);
    VINS2(d0);
    VINS2(d1);
    VINS2(d2);
    VINS2(d3);
    VINS2(d4);
    VINS2(d5);
    VINS2(d6);
    VINS2(d7);
  }
  float* o = &part_v[(size_t)(blockIdx.y * 2) * NPTS + q];
  o[0 * NPTS] = s0;
  o[1 * NPTS] = s1;
}

// ---------------------------------------------------------------------------
// KNN B+C (fused thresh+collect+final+weight-prep): one block per 4 queries.
// Phase T1 (t<32): per query lq=t>>3, chunk c=t&7 merges 8 slices x 2 ranks;
//   slice mins stashed in LDS.
// Phase T2 (t<4): final 64-VINS merge -> tau; inflated thresholds
//   tcol=tau*(1+4e-5), tmask=tau*(1+8e-5); mask = slices with min<=tmask.
// Phase C: one WAVE per query scans its ~8 marked slices; query coords
//   recovered from packed pts4 via exact x*(-0.5); survivors (d<=tcol) ->
//   LDS keybuf via atomics; lane 0 key-sorts and writes nbr
//   (== jax.lax.top_k order).
// First 128 blocks ALSO do the weight bf16-splits.
// ---------------------------------------------------------------------------
__global__ __launch_bounds__(256) void knn_collect_kernel(
    const float4* __restrict__ pts4, const float* __restrict__ part_v,
    int* __restrict__ nbr, const float* __restrict__ W2,
    const float* __restrict__ W3, const float* __restrict__ W4,
    unsigned short* __restrict__ W2th, unsigned short* __restrict__ W2tl,
    unsigned short* __restrict__ W3th, unsigned short* __restrict__ W3tl,
    unsigned short* __restrict__ W4ht, unsigned short* __restrict__ W4lt) {
  __shared__ double keybuf[4][SURV_CAP];
  __shared__ int scnt[4];
  __shared__ float v8s[4][8][9];
  __shared__ float smin[4][65];
  __shared__ float thrS[4];
  __shared__ unsigned long long maskS[4];
  const int t = threadIdx.x;
  if (blockIdx.x < 128) {
    const int id = blockIdx.x * 256 + t;  // 0..32767
    const int k = id >> 8, c = id & 255;
    {
      float v = W4[k * 256 + c];
      unsigned short hi = f2bf(v);
      W4ht[c * 128 + k] = hi;
      W4lt[c * 128 + k] = f2bf(v - bf2f(hi));
    }
    {
      float v3 = (c < 128) ? W3[k * 128 + c] : W3[(128 + k) * 128 + (c - 128)];
      unsigned short h3 = f2bf(v3);
      W3th[c * 128 + k] = h3;
      W3tl[c * 128 + k] = f2bf(v3 - bf2f(h3));
    }
    if (id < NPTS) {
      const int kk = id >> 7, cc = id & 127;
      float v2 = W2[kk * 128 + cc];
      unsigned short h2 = f2bf(v2);
      W2th[cc * 64 + kk] = h2;
      W2tl[cc * 64 + kk] = f2bf(v2 - bf2f(h2));
    }
  }
  const int wv = t >> 6;
  const int lane = t & 63;
  const int q = blockIdx.x * 4 + wv;
  if (lane == 0) scnt[wv] = 0;

  // Phase T1: chunk merges.
  if (t < 32) {
    const int lq = t >> 3, c = t & 7;
    const int qq = blockIdx.x * 4 + lq;
    VDECL;
#pragma unroll
    for (int s8 = 0; s8 < 8; ++s8) {
      const int s = c * 8 + s8;
      const float* col = &part_v[(size_t)(s * 2) * NPTS + qq];
      float a0 = col[0 * (size_t)NPTS];
      float a1 = col[1 * (size_t)NPTS];
      smin[lq][s] = a0;
      VINS(a0);
      VINS(a1);
    }
    v8s[lq][c][0] = v0;
    v8s[lq][c][1] = v1;
    v8s[lq][c][2] = v2;
    v8s[lq][c][3] = v3;
    v8s[lq][c][4] = v4;
    v8s[lq][c][5] = v5;
    v8s[lq][c][6] = v6;
    v8s[lq][c][7] = v7;
  }
  __syncthreads();

  // Phase T2: final merge + thresholds + slice mask (1 thread per query).
  if (t < 4) {
    const int lq = t;
    VDECL;
#pragma unroll
    for (int s = 0; s < 8; ++s) {
      VINS(v8s[lq][s][0]);
      VINS(v8s[lq][s][1]);
      VINS(v8s[lq][s][2]);
      VINS(v8s[lq][s][3]);
      VINS(v8s[lq][s][4]);
      VINS(v8s[lq][s][5]);
      VINS(v8s[lq][s][6]);
      VINS(v8s[lq][s][7]);
    }
    const float tcol = v7 + fabsf(v7) * 4e-5f + 1e-20f;
    const float tmask = v7 + fabsf(v7) * 8e-5f + 2e-20f;
    unsigned long long mk = 0;
#pragma unroll
    for (int s = 0; s < NSLICE; ++s) {
      if (smin[lq][s] <= tmask) mk |= (1ull << s);
    }
    thrS[lq] = tcol;
    maskS[lq] = mk;
  }
  __syncthreads();

  // Phase C: masked scan (query coords: exact -0.5 * packed).
  const float4 qp = pts4[q];
  const float qx = __fmul_rn(-0.5f, qp.x);
  const float qy = __fmul_rn(-0.5f, qp.y);
  const float qz = __fmul_rn(-0.5f, qp.z);
  const float q2 = qp.w;
  const float thrq = thrS[wv];
  unsigned long long m = maskS[wv];
  while (m) {
    const int s = (int)__ffsll(m) - 1;
    m &= m - 1;
    const int base = s * SLICE_LEN;
#pragma unroll
    for (int r = 0; r < SLICE_LEN / 64; ++r) {
      const int j = base + r * 64 + lane;
      const float4 cp = pts4[j];
      const float d = dist_pk(qx, qy, qz, q2, cp.x, cp.y, cp.z, cp.w);
      if (d <= thrq) {
        int slot = atomicAdd(&scnt[wv], 1);
        if (slot < SURV_CAP) keybuf[wv][slot] = pack_key(d, j);
      }
    }
  }
  __syncthreads();
  if (lane == 0) {
    int c = scnt[wv];
    if (c > SURV_CAP) c = SURV_CAP;
    KEY_DECL;
    for (int u = 0; u < c; ++u) {
      KEY_INSERT(keybuf[wv][u]);
    }
    int* o = &nbr[q * KNN];
    o[0] = __double2loint(k0) & 0x1fff;
    o[1] = __double2loint(k1) & 0x1fff;
    o[2] = __double2loint(k2) & 0x1fff;
    o[3] = __double2loint(k3) & 0x1fff;
    o[4] = __double2loint(k4) & 0x1fff;
    o[5] = __double2loint(k5) & 0x1fff;
    o[6] = __double2loint(k6) & 0x1fff;
    o[7] = __double2loint(k7) & 0x1fff;
  }
}

// ---------------------------------------------------------------------------
// Fused EdgeConv1 (MFMA): H1 = relu(e@W1+b1) exact fp32 (K=6), split to
// bf16 hi/lo in LDS; Y-tile = H1@W2 via split-bf16 3-pass MFMA; in-register
// max8 + b2 + relu -> y (8192x128). As r10/r12/r13 (verified).
// ---------------------------------------------------------------------------
__global__ __launch_bounds__(256) void gemm1_fused_kernel(
    const float* __restrict__ pts, const int* __restrict__ nbr,
    const float* __restrict__ W1, const float* __restrict__ b1,
    const unsigned short* __restrict__ W2th,
    const unsigned short* __restrict__ W2tl, const float* __restrict__ b2,
    float* __restrict__ y) {
  __shared__ float es[64][6];
  __shared__ float W1s[6][64];
  __shared__ float b1s[64];
  __shared__ unsigned short H1h[64 * 72];
  __shared__ unsigned short H1l[64 * 72];
  __shared__ unsigned short Wth[64 * 72];
  __shared__ unsigned short Wtl[64 * 72];
  const int t = threadIdx.x;
  const int rowBase = blockIdx.y * 64;
  const int colBase = blockIdx.x * 64;

  for (int idx = t; idx < 384; idx += 256) W1s[idx >> 6][idx & 63] = W1[idx];
  if (t < 64) b1s[t] = b1[t];
  {
    const int colloc = t >> 2, kq = (t & 3) * 16;
    const size_t src = (size_t)(colBase + colloc) * 64 + kq;
    *(uint4*)&Wth[colloc * 72 + kq] = *(const uint4*)&W2th[src];
    *(uint4*)&Wth[colloc * 72 + kq + 8] = *(const uint4*)&W2th[src + 8];
    *(uint4*)&Wtl[colloc * 72 + kq] = *(const uint4*)&W2tl[src];
    *(uint4*)&Wtl[colloc * 72 + kq + 8] = *(const uint4*)&W2tl[src + 8];
  }
  if (t < 64) {
    int e = rowBase + t;
    int i = e >> 3;
    int j = nbr[e];
    float xi0 = pts[i * 3], xi1 = pts[i * 3 + 1], xi2 = pts[i * 3 + 2];
    es[t][0] = xi0;
    es[t][1] = xi1;
    es[t][2] = xi2;
    es[t][3] = pts[j * 3] - xi0;
    es[t][4] = pts[j * 3 + 1] - xi1;
    es[t][5] = pts[j * 3 + 2] - xi2;
  }
  __syncthreads();

  {
    const int e = t & 63, k0 = (t >> 6) * 16;
    const float f0 = es[e][0], f1 = es[e][1], f2 = es[e][2];
    const float f3 = es[e][3], f4 = es[e][4], f5 = es[e][5];
    float h[16];
#pragma unroll
    for (int k = 0; k < 16; ++k) {
      int c = k0 + k;
      float v = b1s[c];
      v = fmaf(f0, W1s[0][c], v);
      v = fmaf(f1, W1s[1][c], v);
      v = fmaf(f2, W1s[2][c], v);
      v = fmaf(f3, W1s[3][c], v);
      v = fmaf(f4, W1s[4][c], v);
      v = fmaf(f5, W1s[5][c], v);
      h[k] = fmaxf(v, 0.0f);
    }
    unsigned int hp[8], lp[8];
#pragma unroll
    for (int u = 0; u < 8; ++u) {
      unsigned short h0 = f2bf(h[2 * u]), h1 = f2bf(h[2 * u + 1]);
      hp[u] = (unsigned int)h0 | ((unsigned int)h1 << 16);
      unsigned short l0 = f2bf(h[2 * u] - bf2f(h0));
      unsigned short l1 = f2bf(h[2 * u + 1] - bf2f(h1));
      lp[u] = (unsigned int)l0 | ((unsigned int)l1 << 16);
    }
    *(uint4*)&H1h[e * 72 + k0] = make_uint4(hp[0], hp[1], hp[2], hp[3]);
    *(uint4*)&H1h[e * 72 + k0 + 8] = make_uint4(hp[4], hp[5], hp[6], hp[7]);
    *(uint4*)&H1l[e * 72 + k0] = make_uint4(lp[0], lp[1], lp[2], lp[3]);
    *(uint4*)&H1l[e * 72 + k0 + 8] = make_uint4(lp[4], lp[5], lp[6], lp[7]);
  }
  __syncthreads();

  const int lane = t & 63, w = t >> 6;
  const int qq = lane >> 4, nidx = lane & 15;
  f32x4 acc[4];
#pragma unroll
  for (int nt = 0; nt < 4; ++nt) acc[nt] = (f32x4){0.f, 0.f, 0.f, 0.f};
  bf16x8 ah0, ah1, al0, al1;
  {
    const int row = w * 16 + nidx;
    ah0 = *(const bf16x8*)&H1h[row * 72 + qq * 8];
    ah1 = *(const bf16x8*)&H1h[row * 72 + 32 + qq * 8];
    al0 = *(const bf16x8*)&H1l[row * 72 + qq * 8];
    al1 = *(const bf16x8*)&H1l[row * 72 + 32 + qq * 8];
  }
#pragma unroll
  for (int nt = 0; nt < 4; ++nt) {
    const int col = nt * 16 + nidx;
    bf16x8 bh0 = *(const bf16x8*)&Wth[col * 72 + qq * 8];
    bf16x8 bh1 = *(const bf16x8*)&Wth[col * 72 + 32 + qq * 8];
    bf16x8 bl0 = *(const bf16x8*)&Wtl[col * 72 + qq * 8];
    bf16x8 bl1 = *(const bf16x8*)&Wtl[col * 72 + 32 + qq * 8];
    acc[nt] = __builtin_amdgcn_mfma_f32_16x16x32_bf16(ah0, bh0, acc[nt], 0, 0, 0);
    acc[nt] = __builtin_amdgcn_mfma_f32_16x16x32_bf16(ah1, bh1, acc[nt], 0, 0, 0);
    acc[nt] = __builtin_amdgcn_mfma_f32_16x16x32_bf16(ah0, bl0, acc[nt], 0, 0, 0);
    acc[nt] = __builtin_amdgcn_mfma_f32_16x16x32_bf16(ah1, bl1, acc[nt], 0, 0, 0);
    acc[nt] = __builtin_amdgcn_mfma_f32_16x16x32_bf16(al0, bh0, acc[nt], 0, 0, 0);
    acc[nt] = __builtin_amdgcn_mfma_f32_16x16x32_bf16(al1, bh1, acc[nt], 0, 0, 0);
  }

  const int pt = blockIdx.y * 8 + 2 * w + (qq >> 1);
#pragma unroll
  for (int nt = 0; nt < 4; ++nt) {
    f32x4 a = acc[nt];
    float m = fmaxf(fmaxf(a[0], a[1]), fmaxf(a[2], a[3]));
    float o = fmaxf(m, __shfl_xor(m, 16, 64));
    if ((qq & 1) == 0) {
      int cg = colBase + nt * 16 + nidx;
      y[(size_t)pt * 128 + cg] = fmaxf(o + b2[cg], 0.0f);
    }
  }
}

// ---------------------------------------------------------------------------
// AC = y @ Wcat (+b3 on cols<128) via split-bf16 3-pass MFMA (r10 verified,
// unchanged: 128 rows x 128 cols per block, grid (2,64)).
// ---------------------------------------------------------------------------
__global__ __launch_bounds__(256) void gemm_ac_mfma_kernel(
    const float* __restrict__ y, const unsigned short* __restrict__ W3th,
    const unsigned short* __restrict__ W3tl, const float* __restrict__ bias,
    float* __restrict__ AC) {
  __shared__ unsigned short Ah[128 * 40];
  __shared__ unsigned short Al[128 * 40];
  __shared__ unsigned short Bh[128 * 40];
  __shared__ unsigned short Bl[128 * 40];
  const int t = threadIdx.x;
  const int rowBase = blockIdx.y * 128;
  const int colBase = blockIdx.x * 128;
  const int eloc = t >> 1, hh = t & 1;
  const int kb = hh * 16;
  const int lane = t & 63, w = t >> 6;
  const int q = lane >> 4, nidx = lane & 15;

  f32x4 acc[2][8];
#pragma unroll
  for (int mt = 0; mt < 2; ++mt)
#pragma unroll
    for (int nt = 0; nt < 8; ++nt) acc[mt][nt] = (f32x4){0.f, 0.f, 0.f, 0.f};

  for (int p = 0; p < 4; ++p) {
    const int k0 = p * 32;
    {
      const float* src = &y[(size_t)(rowBase + eloc) * 128 + k0 + kb];
      float h[16];
      *(float4*)&h[0] = *(const float4*)&src[0];
      *(float4*)&h[4] = *(const float4*)&src[4];
      *(float4*)&h[8] = *(const float4*)&src[8];
      *(float4*)&h[12] = *(const float4*)&src[12];
      unsigned int hp[8], lp[8];
#pragma unroll
      for (int u = 0; u < 8; ++u) {
        unsigned short h0 = f2bf(h[2 * u]), h1 = f2bf(h[2 * u + 1]);
        hp[u] = (unsigned int)h0 | ((unsigned int)h1 << 16);
        unsigned short l0 = f2bf(h[2 * u] - bf2f(h0));
        unsigned short l1 = f2bf(h[2 * u + 1] - bf2f(h1));
        lp[u] = (unsigned int)l0 | ((unsigned int)l1 << 16);
      }
      *(uint4*)&Ah[eloc * 40 + kb] = make_uint4(hp[0], hp[1], hp[2], hp[3]);
      *(uint4*)&Ah[eloc * 40 + kb + 8] = make_uint4(hp[4], hp[5], hp[6], hp[7]);
      *(uint4*)&Al[eloc * 40 + kb] = make_uint4(lp[0], lp[1], lp[2], lp[3]);
      *(uint4*)&Al[eloc * 40 + kb + 8] = make_uint4(lp[4], lp[5], lp[6], lp[7]);
    }
    {
      const size_t src = (size_t)(colBase + eloc) * 128 + k0 + kb;
      *(uint4*)&Bh[eloc * 40 + kb] = *(const uint4*)&W3th[src];
      *(uint4*)&Bh[eloc * 40 + kb + 8] = *(const uint4*)&W3th[src + 8];
      *(uint4*)&Bl[eloc * 40 + kb] = *(const uint4*)&W3tl[src];
      *(uint4*)&Bl[eloc * 40 + kb + 8] = *(const uint4*)&W3tl[src + 8];
    }
    __syncthreads();
    bf16x8 ah[2], al[2];
#pragma unroll
    for (int mt = 0; mt < 2; ++mt) {
      int row = w * 32 + mt * 16 + nidx;
      ah[mt] = *(const bf16x8*)&Ah[row * 40 + q * 8];
      al[mt] = *(const bf16x8*)&Al[row * 40 + q * 8];
    }
#pragma unroll
    for (int nt = 0; nt < 8; ++nt) {
      int col = nt * 16 + nidx;
      bf16x8 bh = *(const bf16x8*)&Bh[col * 40 + q * 8];
      bf16x8 bl = *(const bf16x8*)&Bl[col * 40 + q * 8];
#pragma unroll
      for (int mt = 0; mt < 2; ++mt) {
        acc[mt][nt] = __builtin_amdgcn_mfma_f32_16x16x32_bf16(
            ah[mt], bh, acc[mt][nt], 0, 0, 0);
        acc[mt][nt] = __builtin_amdgcn_mfma_f32_16x16x32_bf16(
            ah[mt], bl, acc[mt][nt], 0, 0, 0);
        acc[mt][nt] = __builtin_amdgcn_mfma_f32_16x16x32_bf16(
            al[mt], bh, acc[mt][nt], 0, 0, 0);
      }
    }
    __syncthreads();
  }

#pragma unroll
  for (int mt = 0; mt < 2; ++mt) {
    const int rowb = rowBase + w * 32 + mt * 16 + q * 4;
#pragma unroll
    for (int nt = 0; nt < 8; ++nt) {
      f32x4 a = acc[mt][nt];
      const int cg = colBase + nt * 16 + nidx;
      const float bb = (cg < 128) ? bias[cg] : 0.0f;
#pragma unroll
      for (int reg = 0; reg < 4; ++reg) {
        AC[(size_t)(rowb + reg) * 256 + cg] = a[reg] + bb;
      }
    }
  }
}

// ---------------------------------------------------------------------------
// MFMA EdgeConv2 second layer (split-bf16), as r10/r12/r13 (verified): 128
// edges x 128 cols per block, grid (2,512).
// ---------------------------------------------------------------------------
__global__ __launch_bounds__(256) void gemm2_mfma_kernel(
    const float* __restrict__ AC, const int* __restrict__ nbr,
    const unsigned short* __restrict__ W4ht,
    const unsigned short* __restrict__ W4lt, const float* __restrict__ b4,
    float* __restrict__ out) {
  __shared__ unsigned short H2h[128 * 40];
  __shared__ unsigned short H2l[128 * 40];
  __shared__ unsigned short Wth[128 * 40];
  __shared__ unsigned short Wtl[128 * 40];
  const int t = threadIdx.x;
  const int rowBase = blockIdx.y * 128;
  const int colBase = blockIdx.x * 128;
  const int eloc = t >> 1, hh = t & 1;
  const int kb = hh * 16;
  const int edge = rowBase + eloc;
  const int ip = edge >> 3;
  const int jp = nbr[edge];
  const float* ai_p = AC + (size_t)ip * 256;
  const float* ci_p = ai_p + 128;
  const float* cj_p = AC + (size_t)jp * 256 + 128;
  const int lane = t & 63;
  const int w = t >> 6;
  const int q = lane >> 4;
  const int nidx = lane & 15;

  f32x4 acc[2][8];
#pragma unroll
  for (int mt = 0; mt < 2; ++mt)
#pragma unroll
    for (int nt = 0; nt < 8; ++nt) acc[mt][nt] = (f32x4){0.f, 0.f, 0.f, 0.f};

  for (int p = 0; p < 4; ++p) {
    const int k0 = p * 32;
    {
      float h2[16];
      const float4* a4 = (const float4*)(ai_p + k0 + kb);
      const float4* c4 = (const float4*)(ci_p + k0 + kb);
      const float4* d4 = (const float4*)(cj_p + k0 + kb);
#pragma unroll
      for (int u = 0; u < 4; ++u) {
        float4 a = a4[u], c = c4[u], d = d4[u];
        h2[u * 4 + 0] = fmaxf(a.x + d.x - c.x, 0.f);
        h2[u * 4 + 1] = fmaxf(a.y + d.y - c.y, 0.f);
        h2[u * 4 + 2] = fmaxf(a.z + d.z - c.z, 0.f);
        h2[u * 4 + 3] = fmaxf(a.w + d.w - c.w, 0.f);
      }
      unsigned int hp[8], lp[8];
#pragma unroll
      for (int u = 0; u < 8; ++u) {
        unsigned short h0 = f2bf(h2[2 * u]), h1 = f2bf(h2[2 * u + 1]);
        hp[u] = (unsigned int)h0 | ((unsigned int)h1 << 16);
        unsigned short l0 = f2bf(h2[2 * u] - bf2f(h0));
        unsigned short l1 = f2bf(h2[2 * u + 1] - bf2f(h1));
        lp[u] = (unsigned int)l0 | ((unsigned int)l1 << 16);
      }
      *(uint4*)&H2h[eloc * 40 + kb] = make_uint4(hp[0], hp[1], hp[2], hp[3]);
      *(uint4*)&H2h[eloc * 40 + kb + 8] =
          make_uint4(hp[4], hp[5], hp[6], hp[7]);
      *(uint4*)&H2l[eloc * 40 + kb] = make_uint4(lp[0], lp[1], lp[2], lp[3]);
      *(uint4*)&H2l[eloc * 40 + kb + 8] =
          make_uint4(lp[4], lp[5], lp[6], lp[7]);
    }
    {
      const size_t src = (size_t)(colBase + eloc) * 128 + k0 + kb;
      *(uint4*)&Wth[eloc * 40 + kb] = *(const uint4*)&W4ht[src];
      *(uint4*)&Wth[eloc * 40 + kb + 8] = *(const uint4*)&W4ht[src + 8];
      *(uint4*)&Wtl[eloc * 40 + kb] = *(const uint4*)&W4lt[src];
      *(uint4*)&Wtl[eloc * 40 + kb + 8] = *(const uint4*)&W4lt[src + 8];
    }
    __syncthreads();
    bf16x8 ah[2], al[2];
#pragma unroll
    for (int mt = 0; mt < 2; ++mt) {
      int row = w * 32 + mt * 16 + nidx;
      ah[mt] = *(const bf16x8*)&H2h[row * 40 + q * 8];
      al[mt] = *(const bf16x8*)&H2l[row * 40 + q * 8];
    }
#pragma unroll
    for (int nt = 0; nt < 8; ++nt) {
      int col = nt * 16 + nidx;
      bf16x8 bh = *(const bf16x8*)&Wth[col * 40 + q * 8];
      bf16x8 bl = *(const bf16x8*)&Wtl[col * 40 + q * 8];
#pragma unroll
      for (int mt = 0; mt < 2; ++mt) {
        acc[mt][nt] = __builtin_amdgcn_mfma_f32_16x16x32_bf16(
            ah[mt], bh, acc[mt][nt], 0, 0, 0);
        acc[mt][nt] = __builtin_amdgcn_mfma_f32_16x16x32_bf16(
            ah[mt], bl, acc[mt][nt], 0, 0, 0);
        acc[mt][nt] = __builtin_amdgcn_mfma_f32_16x16x32_bf16(
            al[mt], bh, acc[mt][nt], 0, 0, 0);
      }
    }
    __syncthreads();
  }

#pragma unroll
  for (int mt = 0; mt < 2; ++mt) {
    const int ebase = rowBase + w * 32 + mt * 16;
    const int pt0 = ebase >> 3;
#pragma unroll
    for (int nt = 0; nt < 8; ++nt) {
      f32x4 a = acc[mt][nt];
      float m = fmaxf(fmaxf(a[0], a[1]), fmaxf(a[2], a[3]));
      float o = fmaxf(m, __shfl_xor(m, 16, 64));
      int cg = colBase + nt * 16 + nidx;
      if (q == 0) {
        out[(size_t)pt0 * 256 + cg] = o + b4[cg];
      } else if (q == 2) {
        out[(size_t)(pt0 + 1) * 256 + cg] = o + b4[cg];
      }
    }
  }
}

extern "C" void kernel_launch(void* const* d_in, const int* in_sizes, int n_in,
                              void* d_out, int out_size, void* d_ws,
                              size_t ws_size, hipStream_t stream) {
  const float* pts = (const float*)d_in[0];
  const float* W1 = (const float*)d_in[1];
  const float* b1 = (const float*)d_in[2];
  const float* W2 = (const float*)d_in[3];
  const float* b2 = (const float*)d_in[4];
  const float* W3 = (const float*)d_in[5];
  const float* b3 = (const float*)d_in[6];
  const float* W4 = (const float*)d_in[7];
  const float* b4 = (const float*)d_in[8];
  float* out = (float*)d_out;

  // Workspace layout (floats), lifetime-overlapped:
  //   part_v [0, 1048576)          : vals->collect (within AC region)
  //   nbr    [4202496, +65536)     : collect->gemm1/gemm2
  //   y      [4268032, +1048576)   : gemm1->gemm_ac
  //   W4ht   [5332992, +16384)
  //   W4lt   [5349376, +16384)
  //   pts4   [5365760, +32768)     : vals->collect (f4[8192], packed -2x)
  //   W2th   [5398528, +4096)      : collect->gemm1 (ushort[8192])
  //   W2tl   [5402624, +4096)      : collect->gemm1 (ushort[8192])
  //   W3th   [5406720, +16384)     : collect->gemm_ac (ushort[32768])
  //   W3tl   [5423104, +16384)     : collect->gemm_ac (ushort[32768])
  //   AC = [0, 2097152) (written after part_v is dead)
  float* w = (float*)d_ws;
  float* part_v = w;
  int* nbr = (int*)(w + 4202496);
  float* y = w + 4268032;
  unsigned short* W4ht = (unsigned short*)(w + 5332992);
  unsigned short* W4lt = (unsigned short*)(w + 5349376);
  float4* pts4 = (float4*)(w + 5365760);
  unsigned short* W2th = (unsigned short*)(w + 5398528);
  unsigned short* W2tl = (unsigned short*)(w + 5402624);
  unsigned short* W3th = (unsigned short*)(w + 5406720);
  unsigned short* W3tl = (unsigned short*)(w + 5423104);
  float* AC = w;

  // 1. KNN: slice top-2 (+packed pts4 publish) -> fused thresh+collect
  //    (+weight bf16-splits in first 128 blocks).
  knn_vals_kernel<<<dim3(32, NSLICE), 256, 0, stream>>>(pts, part_v, pts4);
  knn_collect_kernel<<<2048, 256, 0, stream>>>(pts4, part_v, nbr, W2, W3, W4,
                                               W2th, W2tl, W3th, W3tl, W4ht,
                                               W4lt);

  // 2. EdgeConv1 (MFMA H1@W2 + max8 + b2 + relu), r10 half-width blocks.
  gemm1_fused_kernel<<<dim3(2, 1024), 256, 0, stream>>>(pts, nbr, W1, b1,
                                                        W2th, W2tl, b2, y);

  // 3. EdgeConv2: AC = y@Wcat (+b3) via MFMA, then r10 MFMA
  //    H2+GEMM+max8+b4 -> out.
  gemm_ac_mfma_kernel<<<dim3(2, 64), 256, 0, stream>>>(y, W3th, W3tl, b3, AC);
  gemm2_mfma_kernel<<<dim3(2, 512), 256, 0, stream>>>(AC, nbr, W4ht, W4lt, b4,
                                                      out);
}